// Round 1
// baseline (334.607 us; speedup 1.0000x reference)
//
#include <hip/hip_runtime.h>

#define N_NODES 50000
#define N_EDGES 600000
#define DH 128
#define DOUT 64
#define NG 64
#define SLOPE 0.2f
#define LB 391   // GEMM blocks: (N_NODES+127)/128

using short8  = __attribute__((ext_vector_type(8))) short;
using floatx4 = __attribute__((ext_vector_type(4))) float;

__device__ __forceinline__ float leaky(float v){ return fmaxf(v, SLOPE*v); }
__device__ __forceinline__ unsigned f2bf(float x){
  unsigned u = __float_as_uint(x);
  return (u + 0x7fffu + ((u>>16)&1u)) >> 16;          // RNE bf16
}
#if __has_builtin(__builtin_amdgcn_cvt_pk_bf16_f32)
__device__ __forceinline__ unsigned pack2bf(float a, float b){
  auto t = __builtin_amdgcn_cvt_pk_bf16_f32(a, b);
  unsigned u; __builtin_memcpy(&u, &t, 4); return u;
}
#else
__device__ __forceinline__ unsigned pack2bf(float a, float b){
  return f2bf(a) | (f2bf(b) << 16);
}
#endif
__device__ __forceinline__ float bf_lo(unsigned u){ return __uint_as_float(u<<16); }
__device__ __forceinline__ float bf_hi(unsigned u){ return __uint_as_float(u & 0xffff0000u); }
__device__ __forceinline__ float rl_f(float v, int l){
  return __uint_as_float(__builtin_amdgcn_readlane(__float_as_uint(v), l));
}
__device__ __forceinline__ int rl_i(int v, int l){
  return __builtin_amdgcn_readlane(v, l);
}

// ---------------- CSR build + weight prep + graph boundaries ---------------------------
// k_hist also performs the Wt transpose+cast AND the per-graph boundary scan (gstart),
// all independent work riding one launch.
__global__ __launch_bounds__(256)
void k_hist(const int* __restrict__ dst, int* __restrict__ counts,
            int* __restrict__ rank,
            const float* __restrict__ W1, const float* __restrict__ Wg,
            unsigned short* __restrict__ Wt,
            const int* __restrict__ batch, int* __restrict__ gstart){
  int gid = blockIdx.x*256 + threadIdx.x;
  if (gid < 4*16384){                          // weight prep rides along
    int mi = gid >> 14, r = gid & 16383;
    int k = r >> 7, n = r & 127;
    const float* src = (mi==0) ? W1 : (Wg + (size_t)(mi-1)*16384);
    Wt[(size_t)mi*16384 + (size_t)n*128 + k] = (unsigned short)f2bf(src[k*128 + n]);
  }
  int stride = gridDim.x*256;
  for (int e = gid; e < N_EDGES; e += stride){
    rank[e] = atomicAdd(&counts[dst[e]], 1);
  }
  // graph boundaries from sorted batch: gstart[g] = first node with batch >= g
  for (int n = gid; n < N_NODES; n += stride){
    int b  = batch[n];
    int bp = (n == 0) ? -1 : batch[n-1];
    if (b != bp){
      for (int g = bp+1; g <= b; g++) gstart[g] = n;
    }
    if (n == N_NODES-1){
      for (int g = b+1; g <= NG; g++) gstart[g] = N_NODES;
    }
  }
}

// phase 2+3 fused: each block redundantly prefix-sums the nb block sums (<=25 adds),
// then does its local exclusive scan + propagate. (25 blocks, 256 threads)
__global__ __launch_bounds__(256)
void k_bscan3(const int* __restrict__ counts, const int* __restrict__ bsum,
              int* __restrict__ row_ptr, int nb){
  __shared__ int sb[256];
  __shared__ int sbs[64];
  int t = threadIdx.x;
  if (t < nb) sbs[t] = bsum[t];
  int base = blockIdx.x*2048;
  int c[8]; int s=0;
  #pragma unroll
  for (int j=0;j<8;j++){ int i = base+t*8+j; c[j] = (i<N_NODES)? counts[i]:0; s += c[j]; }
  sb[t]=s; __syncthreads();
  for (int off=1; off<256; off<<=1){
    int v = (t>=off)? sb[t-off] : 0;
    __syncthreads();
    sb[t]+=v;
    __syncthreads();
  }
  int boffv = 0;
  for (int b=0;b<(int)blockIdx.x;b++) boffv += sbs[b];
  int run = sb[t]-s + boffv;
  #pragma unroll
  for (int j=0;j<8;j++){
    int i = base+t*8+j;
    if (i<N_NODES){ row_ptr[i]=run; run+=c[j]; }
  }
  if ((int)blockIdx.x == nb-1 && t == 0){
    row_ptr[N_NODES] = boffv + sbs[nb-1];      // == N_EDGES
  }
}

// ---------------- MFMA GEMM body (transposed D): out[node][feat] bf16, fused es/ed -----
// 512 thr / 8 waves / 128 nodes per block. Wt: [n][k] bf16 staged in LDS (+8 pad).
// mfma(A=Wt frag, B=node frag): D[m=feature][n=node]; C/D: col(node)=lane&15,
// row(feature)=quad*4+reg -> each lane owns 4 CONSECUTIVE features per nt tile.
template<bool AFP32>
__device__ __forceinline__
void lin_body(const void* __restrict__ Av,
              const unsigned short* __restrict__ Wt,
              const float* __restrict__ bias,
              const float* __restrict__ avs, const float* __restrict__ avd,
              unsigned short* __restrict__ outB,
              float* __restrict__ es, float* __restrict__ ed, int nrows,
              int bid, unsigned short* wlds){
  int tid = threadIdx.x;
  #pragma unroll
  for (int i=0;i<4;i++){
    int flat = i*4096 + tid*8;
    int n = flat >> 7, kb = flat & 127;
    *(short8*)&wlds[n*136 + kb] = *(const short8*)(Wt + flat);
  }
  __syncthreads();

  int wid = tid >> 6, lane = tid & 63;
  int l15 = lane & 15, quad = lane >> 4;
  int R0 = bid*128 + wid*16;
  int node = R0 + l15;
  int arow = node < nrows ? node : nrows-1;

  floatx4 acc[8];
  #pragma unroll
  for (int nt=0;nt<8;nt++){ acc[nt][0]=0.f; acc[nt][1]=0.f; acc[nt][2]=0.f; acc[nt][3]=0.f; }

  #pragma unroll
  for (int k0=0;k0<128;k0+=32){
    short8 a;                                   // node fragment (B operand)
    if (AFP32){
      const float* Ap = (const float*)Av + (size_t)arow*128 + quad*8 + k0;
      float4 v0 = *(const float4*)Ap;
      float4 v1 = *(const float4*)(Ap+4);
      union { short8 s; unsigned u[4]; } cv;
      cv.u[0]=pack2bf(v0.x,v0.y); cv.u[1]=pack2bf(v0.z,v0.w);
      cv.u[2]=pack2bf(v1.x,v1.y); cv.u[3]=pack2bf(v1.z,v1.w);
      a = cv.s;
    } else {
      a = *(const short8*)((const unsigned short*)Av + (size_t)arow*128 + quad*8 + k0);
    }
    const unsigned short* bp = &wlds[l15*136 + quad*8 + k0];
    #pragma unroll
    for (int nt=0;nt<8;nt++){
      short8 b = *(const short8*)(bp + nt*16*136);   // Wt fragment (A operand)
      acc[nt] = __builtin_amdgcn_mfma_f32_16x16x32_bf16(b, a, acc[nt], 0,0,0);
    }
  }

  bool nv = node < nrows;
  float ps = 0.f, pd = 0.f;
  #pragma unroll
  for (int nt=0;nt<8;nt++){
    int f0 = nt*16 + quad*4;                  // 4 consecutive features for this lane
    float4 bb = make_float4(0.f,0.f,0.f,0.f);
    if (bias) bb = *(const float4*)(bias + f0);
    float v0 = acc[nt][0]+bb.x, v1 = acc[nt][1]+bb.y;
    float v2 = acc[nt][2]+bb.z, v3 = acc[nt][3]+bb.w;
    if (es){
      float4 a4 = *(const float4*)(avs + f0);
      float4 d4 = *(const float4*)(avd + f0);
      ps = fmaf(v0,a4.x, fmaf(v1,a4.y, fmaf(v2,a4.z, fmaf(v3,a4.w, ps))));
      pd = fmaf(v0,d4.x, fmaf(v1,d4.y, fmaf(v2,d4.z, fmaf(v3,d4.w, pd))));
    }
    if (nv){
      uint2 pk; pk.x = pack2bf(v0,v1); pk.y = pack2bf(v2,v3);
      *(uint2*)(outB + (size_t)node*128 + f0) = pk;
    }
  }
  if (es){
    ps += __shfl_xor(ps, 16, 64); ps += __shfl_xor(ps, 32, 64);
    pd += __shfl_xor(pd, 16, 64); pd += __shfl_xor(pd, 32, 64);
    if (quad==0 && nv){ es[node]=ps; ed[node]=pd; }
  }
}

template<bool AFP32>
__global__ __launch_bounds__(512)
void k_linear_mfma(const void* __restrict__ Av,
                   const unsigned short* __restrict__ Wt,
                   const float* __restrict__ bias,
                   const float* __restrict__ avs, const float* __restrict__ avd,
                   unsigned short* __restrict__ outB,
                   float* __restrict__ es, float* __restrict__ ed, int nrows){
  __shared__ unsigned short wlds[128*136];
  lin_body<AFP32>(Av, Wt, bias, avs, avd, outB, es, ed, nrows, blockIdx.x, wlds);
}

// ---------------- fat kernel: mlp1 GEMM (blocks <LB) ∥ scan phase-1 (blocks >=LB) ------
__global__ __launch_bounds__(512)
void k_lin1_scan1(const float* __restrict__ x, const unsigned short* __restrict__ Wt,
                  const float* __restrict__ b1, unsigned short* __restrict__ hbf,
                  const int* __restrict__ counts, int* __restrict__ bsum){
  if ((int)blockIdx.x >= LB){
    __shared__ int sb1[512];
    int sbid = blockIdx.x - LB;
    int base = sbid*2048;
    int t = threadIdx.x;
    int s = 0;
    #pragma unroll
    for (int j=0;j<4;j++){ int i = base + t*4 + j; if (i < N_NODES) s += counts[i]; }
    sb1[t]=s; __syncthreads();
    for (int off=256; off>0; off>>=1){ if (t<off) sb1[t]+=sb1[t+off]; __syncthreads(); }
    if (t==0) bsum[sbid]=sb1[0];
    return;
  }
  __shared__ unsigned short wlds[128*136];
  lin_body<true>(x, Wt, b1, nullptr, nullptr, hbf, nullptr, nullptr, N_NODES,
                 blockIdx.x, wlds);
}

// ---------------- fat kernel: layer-0 GEMM (blocks <LB) ∥ CSR scatter (blocks >=LB) ----
__global__ __launch_bounds__(512)
void k_lin_scatter(const unsigned short* __restrict__ hbf,
                   const unsigned short* __restrict__ Wt,
                   const float* __restrict__ avs, const float* __restrict__ avd,
                   unsigned short* __restrict__ hp,
                   float* __restrict__ es, float* __restrict__ ed,
                   const int* __restrict__ esrc, const int* __restrict__ edst,
                   const int* __restrict__ rank, const int* __restrict__ row_ptr,
                   int* __restrict__ col_src){
  if ((int)blockIdx.x >= LB){
    int e0 = (blockIdx.x - LB)*512 + threadIdx.x;
    const int stride = (1024 - LB)*512;
    for (int e = e0; e < N_EDGES; e += stride){
      col_src[row_ptr[edst[e]] + rank[e]] = esrc[e];
    }
    return;
  }
  __shared__ unsigned short wlds[128*136];
  lin_body<false>(hbf, Wt, nullptr, avs, avd, hp, es, ed, N_NODES, blockIdx.x, wlds);
}

// ---------------- GAT aggregation: wave/node grid-stride, bf16 gather ------------------
#define AGG_BLOCKS 3126
__global__ __launch_bounds__(256)
void k_gat_agg(const unsigned* __restrict__ hp2, const float* __restrict__ es,
               const float* __restrict__ ed, const int* __restrict__ row_ptr,
               const int* __restrict__ col_src, const float* __restrict__ bg,
               unsigned* __restrict__ hbf2){
  int lane = threadIdx.x & 63;
  int wav0 = blockIdx.x*4 + (threadIdx.x >> 6);
  const int NW = AGG_BLOCKS*4;
  float2 bgv = *(const float2*)&bg[2*lane];

  for (int i = wav0; i < N_NODES; i += NW){
    int start = row_ptr[i], end = row_ptr[i+1];
    float edi = ed[i];
    float m0 = leaky(es[i] + edi);              // self score: softmax recentering
    unsigned us = hp2[((unsigned)i<<6) | lane];
    float acc0 = bf_lo(us), acc1 = bf_hi(us);   // self weight exp(0)=1
    float zl = (lane==0) ? 1.f : 0.f;

    for (int c0 = start; c0 < end; c0 += 64){
      int j = c0 + lane;
      bool valid = j < end;
      int s = valid ? col_src[j] : 0;
      float e = leaky(es[s] + edi);
      float w = valid ? __expf(e - m0) : 0.f;
      zl += w;
      int len = end - c0; if (len > 64) len = 64;
      int t = 0;
      for (; t + 8 <= len; t += 8){
        unsigned o0=((unsigned)rl_i(s,t  )<<6)|lane, o1=((unsigned)rl_i(s,t+1)<<6)|lane;
        unsigned o2=((unsigned)rl_i(s,t+2)<<6)|lane, o3=((unsigned)rl_i(s,t+3)<<6)|lane;
        unsigned o4=((unsigned)rl_i(s,t+4)<<6)|lane, o5=((unsigned)rl_i(s,t+5)<<6)|lane;
        unsigned o6=((unsigned)rl_i(s,t+6)<<6)|lane, o7=((unsigned)rl_i(s,t+7)<<6)|lane;
        unsigned u0=hp2[o0], u1=hp2[o1], u2=hp2[o2], u3=hp2[o3];
        unsigned u4=hp2[o4], u5=hp2[o5], u6=hp2[o6], u7=hp2[o7];
        float w0=rl_f(w,t),   w1=rl_f(w,t+1), w2=rl_f(w,t+2), w3=rl_f(w,t+3);
        float w4=rl_f(w,t+4), w5=rl_f(w,t+5), w6=rl_f(w,t+6), w7=rl_f(w,t+7);
        acc0 = fmaf(w0, bf_lo(u0), acc0); acc1 = fmaf(w0, bf_hi(u0), acc1);
        acc0 = fmaf(w1, bf_lo(u1), acc0); acc1 = fmaf(w1, bf_hi(u1), acc1);
        acc0 = fmaf(w2, bf_lo(u2), acc0); acc1 = fmaf(w2, bf_hi(u2), acc1);
        acc0 = fmaf(w3, bf_lo(u3), acc0); acc1 = fmaf(w3, bf_hi(u3), acc1);
        acc0 = fmaf(w4, bf_lo(u4), acc0); acc1 = fmaf(w4, bf_hi(u4), acc1);
        acc0 = fmaf(w5, bf_lo(u5), acc0); acc1 = fmaf(w5, bf_hi(u5), acc1);
        acc0 = fmaf(w6, bf_lo(u6), acc0); acc1 = fmaf(w6, bf_hi(u6), acc1);
        acc0 = fmaf(w7, bf_lo(u7), acc0); acc1 = fmaf(w7, bf_hi(u7), acc1);
      }
      for (; t + 4 <= len; t += 4){
        unsigned o0=((unsigned)rl_i(s,t  )<<6)|lane, o1=((unsigned)rl_i(s,t+1)<<6)|lane;
        unsigned o2=((unsigned)rl_i(s,t+2)<<6)|lane, o3=((unsigned)rl_i(s,t+3)<<6)|lane;
        unsigned u0=hp2[o0], u1=hp2[o1], u2=hp2[o2], u3=hp2[o3];
        float w0=rl_f(w,t), w1=rl_f(w,t+1), w2=rl_f(w,t+2), w3=rl_f(w,t+3);
        acc0 = fmaf(w0, bf_lo(u0), acc0); acc1 = fmaf(w0, bf_hi(u0), acc1);
        acc0 = fmaf(w1, bf_lo(u1), acc0); acc1 = fmaf(w1, bf_hi(u1), acc1);
        acc0 = fmaf(w2, bf_lo(u2), acc0); acc1 = fmaf(w2, bf_hi(u2), acc1);
        acc0 = fmaf(w3, bf_lo(u3), acc0); acc1 = fmaf(w3, bf_hi(u3), acc1);
      }
      for (; t < len; t++){
        unsigned u = hp2[((unsigned)rl_i(s,t)<<6) | lane];
        float wt = rl_f(w,t);
        acc0 = fmaf(wt, bf_lo(u), acc0);
        acc1 = fmaf(wt, bf_hi(u), acc1);
      }
    }

    float z = zl;
    #pragma unroll
    for (int off=32; off>0; off>>=1) z += __shfl_xor(z, off, 64);
    float inv = 1.f / z;
    float r0 = fmaf(acc0, inv, bgv.x);
    float r1 = fmaf(acc1, inv, bgv.y);
    r0 = r0 > 0.f ? r0 : 0.f;
    r1 = r1 > 0.f ? r1 : 0.f;
    unsigned ho = hbf2[((unsigned)i<<6) | lane];   // residual (bf16 stream)
    hbf2[((unsigned)i<<6) | lane] = pack2bf(r0 + bf_lo(ho), r1 + bf_hi(ho));
  }
}

// ---------------- fused global_add_pool + final linear (one block per graph) -----------
// batch sorted -> gstart boundaries precomputed in k_hist. No atomics, no pooled buffer.
__global__ __launch_bounds__(256)
void k_pool_final(const unsigned* __restrict__ hbf2, const int* __restrict__ gstart,
                  const float* __restrict__ W2, const float* __restrict__ b2,
                  float* __restrict__ out){
  __shared__ float part[4][128];
  __shared__ float pl[128];
  int g = blockIdx.x;
  int tid = threadIdx.x, lane = tid & 63, w = tid >> 6;
  int s0 = gstart[g], s1 = gstart[g+1];
  float a0 = 0.f, a1 = 0.f;
  for (int n = s0 + w; n < s1; n += 4){
    unsigned u = hbf2[((unsigned)n<<6) | lane];
    a0 += bf_lo(u); a1 += bf_hi(u);
  }
  part[w][2*lane] = a0; part[w][2*lane+1] = a1;
  __syncthreads();
  if (tid < 128) pl[tid] = part[0][tid]+part[1][tid]+part[2][tid]+part[3][tid];
  __syncthreads();
  if (tid < DOUT){
    float acc = b2[tid];
    #pragma unroll 8
    for (int k=0;k<DH;k++) acc = fmaf(pl[k], W2[k*DOUT + tid], acc);
    out[(size_t)g*DOUT + tid] = acc;
  }
}

extern "C" void kernel_launch(void* const* d_in, const int* in_sizes, int n_in,
                              void* d_out, int out_size, void* d_ws, size_t ws_size,
                              hipStream_t stream){
  const float* x     = (const float*)d_in[0];
  const int*   ei    = (const int*)d_in[1];
  const int*   batch = (const int*)d_in[2];
  const float* W1    = (const float*)d_in[3];
  const float* b1    = (const float*)d_in[4];
  const float* Wg    = (const float*)d_in[5];
  const float* avs   = (const float*)d_in[6];
  const float* avd   = (const float*)d_in[7];
  const float* bgv   = (const float*)d_in[8];
  const float* W2    = (const float*)d_in[9];
  const float* b2    = (const float*)d_in[10];
  float* out = (float*)d_out;

  char* ws = (char*)d_ws;
  unsigned short* hbf = (unsigned short*)ws;       ws += (size_t)N_NODES*DH*2;   // residual stream (bf16)
  unsigned short* hp  = (unsigned short*)ws;       ws += (size_t)N_NODES*DH*2;   // GEMM out (bf16)
  float* es       = (float*)ws;                    ws += (size_t)N_NODES*4;
  float* ed       = (float*)ws;                    ws += (size_t)N_NODES*4;
  unsigned short* Wt = (unsigned short*)ws;        ws += 4*16384*2;
  int* counts     = (int*)ws;                      ws += (size_t)N_NODES*4;
  int* row_ptr    = (int*)ws;                      ws += ((size_t)N_NODES+1)*4;
  int* rank       = (int*)ws;                      ws += (size_t)N_EDGES*4;
  int* col_src    = (int*)ws;                      ws += (size_t)N_EDGES*4;
  int* bsum       = (int*)ws;                      ws += 64*4;
  int* gstart     = (int*)ws;                      ws += 68*4;

  const int* esrc = ei;
  const int* edst = ei + N_EDGES;

  hipMemsetAsync(counts, 0, N_NODES*sizeof(int), stream);

  // K1: edge histogram + weight transpose/cast + graph boundary scan
  k_hist<<<1024, 256, 0, stream>>>(edst, counts, rank, W1, Wg, Wt, batch, gstart);
  // K2: mlp1 GEMM (391 blocks) overlapped with scan phase-1 (25 blocks)
  k_lin1_scan1<<<LB + 25, 512, 0, stream>>>(x, Wt, b1, hbf, counts, bsum);
  // K3: scan phase-2+3 (only exposed CSR cost, ~4 us)
  k_bscan3<<<25, 256, 0, stream>>>(counts, bsum, row_ptr, 25);
  // K4: layer-0 GEMM + es/ed (391 blocks) overlapped with CSR scatter (633 blocks)
  k_lin_scatter<<<1024, 512, 0, stream>>>(hbf, Wt + 16384, avs, avd,
                                          hp, es, ed, esrc, edst, rank, row_ptr, col_src);
  // K5: layer-0 aggregation
  k_gat_agg<<<AGG_BLOCKS, 256, 0, stream>>>((const unsigned*)hp, es, ed,
                                            row_ptr, col_src, bgv, (unsigned*)hbf);
  // layers 1,2
  for (int l = 1; l < 3; l++){
    k_linear_mfma<false><<<LB, 512, 0, stream>>>(hbf, Wt + (size_t)(l+1)*16384, nullptr,
                                                 avs + l*DH, avd + l*DH,
                                                 hp, es, ed, N_NODES);
    k_gat_agg<<<AGG_BLOCKS, 256, 0, stream>>>((const unsigned*)hp, es, ed,
                                              row_ptr, col_src, bgv + l*DH,
                                              (unsigned*)hbf);
  }
  // K10: fused pool + final linear (one block per graph, no atomics)
  k_pool_final<<<NG, 256, 0, stream>>>((const unsigned*)hbf, gstart, W2, b2, out);
}

// Round 2
// 301.020 us; speedup vs baseline: 1.1116x; 1.1116x over previous
//
#include <hip/hip_runtime.h>

#define N_NODES 50000
#define N_EDGES 600000
#define DH 128
#define DOUT 64
#define NG 64
#define SLOPE 0.2f
#define LB 391   // GEMM blocks: (N_NODES+127)/128

using short8  = __attribute__((ext_vector_type(8))) short;
using floatx4 = __attribute__((ext_vector_type(4))) float;

__device__ __forceinline__ float leaky(float v){ return fmaxf(v, SLOPE*v); }
__device__ __forceinline__ unsigned f2bf(float x){
  unsigned u = __float_as_uint(x);
  return (u + 0x7fffu + ((u>>16)&1u)) >> 16;          // RNE bf16
}
#if __has_builtin(__builtin_amdgcn_cvt_pk_bf16_f32)
__device__ __forceinline__ unsigned pack2bf(float a, float b){
  auto t = __builtin_amdgcn_cvt_pk_bf16_f32(a, b);
  unsigned u; __builtin_memcpy(&u, &t, 4); return u;
}
#else
__device__ __forceinline__ unsigned pack2bf(float a, float b){
  return f2bf(a) | (f2bf(b) << 16);
}
#endif
__device__ __forceinline__ float bf_lo(unsigned u){ return __uint_as_float(u<<16); }
__device__ __forceinline__ float bf_hi(unsigned u){ return __uint_as_float(u & 0xffff0000u); }
__device__ __forceinline__ float rl_f(float v, int l){
  return __uint_as_float(__builtin_amdgcn_readlane(__float_as_uint(v), l));
}
__device__ __forceinline__ int rl_i(int v, int l){
  return __builtin_amdgcn_readlane(v, l);
}

// ---------------- CSR build + weight prep ----------------------------------------------
// k_hist also performs the Wt transpose+cast (independent work riding one launch).
// NOTE (R1 lesson): do NOT fuse pool+final into one 64-block kernel — 2.2% occupancy,
// latency-bound, 64 us. k_pool's 391-block run-accumulation shape is the right one.
__global__ __launch_bounds__(256)
void k_hist(const int* __restrict__ dst, int* __restrict__ counts,
            int* __restrict__ rank,
            const float* __restrict__ W1, const float* __restrict__ Wg,
            unsigned short* __restrict__ Wt){
  int gid = blockIdx.x*256 + threadIdx.x;
  if (gid < 4*16384){                          // weight prep rides along
    int mi = gid >> 14, r = gid & 16383;
    int k = r >> 7, n = r & 127;
    const float* src = (mi==0) ? W1 : (Wg + (size_t)(mi-1)*16384);
    Wt[(size_t)mi*16384 + (size_t)n*128 + k] = (unsigned short)f2bf(src[k*128 + n]);
  }
  int stride = gridDim.x*256;
  for (int e = gid; e < N_EDGES; e += stride){
    rank[e] = atomicAdd(&counts[dst[e]], 1);
  }
}

// phase 2+3 fused: each block redundantly prefix-sums the nb block sums (<=25 adds),
// then does its local exclusive scan + propagate. (25 blocks, 256 threads)
__global__ __launch_bounds__(256)
void k_bscan3(const int* __restrict__ counts, const int* __restrict__ bsum,
              int* __restrict__ row_ptr, int nb){
  __shared__ int sb[256];
  __shared__ int sbs[64];
  int t = threadIdx.x;
  if (t < nb) sbs[t] = bsum[t];
  int base = blockIdx.x*2048;
  int c[8]; int s=0;
  #pragma unroll
  for (int j=0;j<8;j++){ int i = base+t*8+j; c[j] = (i<N_NODES)? counts[i]:0; s += c[j]; }
  sb[t]=s; __syncthreads();
  for (int off=1; off<256; off<<=1){
    int v = (t>=off)? sb[t-off] : 0;
    __syncthreads();
    sb[t]+=v;
    __syncthreads();
  }
  int boffv = 0;
  for (int b=0;b<(int)blockIdx.x;b++) boffv += sbs[b];
  int run = sb[t]-s + boffv;
  #pragma unroll
  for (int j=0;j<8;j++){
    int i = base+t*8+j;
    if (i<N_NODES){ row_ptr[i]=run; run+=c[j]; }
  }
  if ((int)blockIdx.x == nb-1 && t == 0){
    row_ptr[N_NODES] = boffv + sbs[nb-1];      // == N_EDGES
  }
}

// ---------------- MFMA GEMM body (transposed D): out[node][feat] bf16, fused es/ed -----
// 512 thr / 8 waves / 128 nodes per block. Wt: [n][k] bf16 staged in LDS (+8 pad).
// mfma(A=Wt frag, B=node frag): D[m=feature][n=node]; C/D: col(node)=lane&15,
// row(feature)=quad*4+reg -> each lane owns 4 CONSECUTIVE features per nt tile.
template<bool AFP32>
__device__ __forceinline__
void lin_body(const void* __restrict__ Av,
              const unsigned short* __restrict__ Wt,
              const float* __restrict__ bias,
              const float* __restrict__ avs, const float* __restrict__ avd,
              unsigned short* __restrict__ outB,
              float* __restrict__ es, float* __restrict__ ed, int nrows,
              int bid, unsigned short* wlds){
  int tid = threadIdx.x;
  #pragma unroll
  for (int i=0;i<4;i++){
    int flat = i*4096 + tid*8;
    int n = flat >> 7, kb = flat & 127;
    *(short8*)&wlds[n*136 + kb] = *(const short8*)(Wt + flat);
  }
  __syncthreads();

  int wid = tid >> 6, lane = tid & 63;
  int l15 = lane & 15, quad = lane >> 4;
  int R0 = bid*128 + wid*16;
  int node = R0 + l15;
  int arow = node < nrows ? node : nrows-1;

  floatx4 acc[8];
  #pragma unroll
  for (int nt=0;nt<8;nt++){ acc[nt][0]=0.f; acc[nt][1]=0.f; acc[nt][2]=0.f; acc[nt][3]=0.f; }

  #pragma unroll
  for (int k0=0;k0<128;k0+=32){
    short8 a;                                   // node fragment (B operand)
    if (AFP32){
      const float* Ap = (const float*)Av + (size_t)arow*128 + quad*8 + k0;
      float4 v0 = *(const float4*)Ap;
      float4 v1 = *(const float4*)(Ap+4);
      union { short8 s; unsigned u[4]; } cv;
      cv.u[0]=pack2bf(v0.x,v0.y); cv.u[1]=pack2bf(v0.z,v0.w);
      cv.u[2]=pack2bf(v1.x,v1.y); cv.u[3]=pack2bf(v1.z,v1.w);
      a = cv.s;
    } else {
      a = *(const short8*)((const unsigned short*)Av + (size_t)arow*128 + quad*8 + k0);
    }
    const unsigned short* bp = &wlds[l15*136 + quad*8 + k0];
    #pragma unroll
    for (int nt=0;nt<8;nt++){
      short8 b = *(const short8*)(bp + nt*16*136);   // Wt fragment (A operand)
      acc[nt] = __builtin_amdgcn_mfma_f32_16x16x32_bf16(b, a, acc[nt], 0,0,0);
    }
  }

  bool nv = node < nrows;
  float ps = 0.f, pd = 0.f;
  #pragma unroll
  for (int nt=0;nt<8;nt++){
    int f0 = nt*16 + quad*4;                  // 4 consecutive features for this lane
    float4 bb = make_float4(0.f,0.f,0.f,0.f);
    if (bias) bb = *(const float4*)(bias + f0);
    float v0 = acc[nt][0]+bb.x, v1 = acc[nt][1]+bb.y;
    float v2 = acc[nt][2]+bb.z, v3 = acc[nt][3]+bb.w;
    if (es){
      float4 a4 = *(const float4*)(avs + f0);
      float4 d4 = *(const float4*)(avd + f0);
      ps = fmaf(v0,a4.x, fmaf(v1,a4.y, fmaf(v2,a4.z, fmaf(v3,a4.w, ps))));
      pd = fmaf(v0,d4.x, fmaf(v1,d4.y, fmaf(v2,d4.z, fmaf(v3,d4.w, pd))));
    }
    if (nv){
      uint2 pk; pk.x = pack2bf(v0,v1); pk.y = pack2bf(v2,v3);
      *(uint2*)(outB + (size_t)node*128 + f0) = pk;
    }
  }
  if (es){
    ps += __shfl_xor(ps, 16, 64); ps += __shfl_xor(ps, 32, 64);
    pd += __shfl_xor(pd, 16, 64); pd += __shfl_xor(pd, 32, 64);
    if (quad==0 && nv){ es[node]=ps; ed[node]=pd; }
  }
}

template<bool AFP32>
__global__ __launch_bounds__(512)
void k_linear_mfma(const void* __restrict__ Av,
                   const unsigned short* __restrict__ Wt,
                   const float* __restrict__ bias,
                   const float* __restrict__ avs, const float* __restrict__ avd,
                   unsigned short* __restrict__ outB,
                   float* __restrict__ es, float* __restrict__ ed, int nrows){
  __shared__ unsigned short wlds[128*136];
  lin_body<AFP32>(Av, Wt, bias, avs, avd, outB, es, ed, nrows, blockIdx.x, wlds);
}

// ---------------- fat kernel: mlp1 GEMM (blocks <LB) ∥ scan phase-1 (blocks >=LB) ------
__global__ __launch_bounds__(512)
void k_lin1_scan1(const float* __restrict__ x, const unsigned short* __restrict__ Wt,
                  const float* __restrict__ b1, unsigned short* __restrict__ hbf,
                  const int* __restrict__ counts, int* __restrict__ bsum){
  if ((int)blockIdx.x >= LB){
    __shared__ int sb1[512];
    int sbid = blockIdx.x - LB;
    int base = sbid*2048;
    int t = threadIdx.x;
    int s = 0;
    #pragma unroll
    for (int j=0;j<4;j++){ int i = base + t*4 + j; if (i < N_NODES) s += counts[i]; }
    sb1[t]=s; __syncthreads();
    for (int off=256; off>0; off>>=1){ if (t<off) sb1[t]+=sb1[t+off]; __syncthreads(); }
    if (t==0) bsum[sbid]=sb1[0];
    return;
  }
  __shared__ unsigned short wlds[128*136];
  lin_body<true>(x, Wt, b1, nullptr, nullptr, hbf, nullptr, nullptr, N_NODES,
                 blockIdx.x, wlds);
}

// ---------------- fat kernel: layer-0 GEMM (blocks <LB) ∥ CSR scatter (blocks >=LB) ----
__global__ __launch_bounds__(512)
void k_lin_scatter(const unsigned short* __restrict__ hbf,
                   const unsigned short* __restrict__ Wt,
                   const float* __restrict__ avs, const float* __restrict__ avd,
                   unsigned short* __restrict__ hp,
                   float* __restrict__ es, float* __restrict__ ed,
                   const int* __restrict__ esrc, const int* __restrict__ edst,
                   const int* __restrict__ rank, const int* __restrict__ row_ptr,
                   int* __restrict__ col_src){
  if ((int)blockIdx.x >= LB){
    int e0 = (blockIdx.x - LB)*512 + threadIdx.x;
    const int stride = (1024 - LB)*512;
    for (int e = e0; e < N_EDGES; e += stride){
      col_src[row_ptr[edst[e]] + rank[e]] = esrc[e];
    }
    return;
  }
  __shared__ unsigned short wlds[128*136];
  lin_body<false>(hbf, Wt, nullptr, avs, avd, hp, es, ed, N_NODES, blockIdx.x, wlds);
}

// ---------------- GAT aggregation: wave/node grid-stride, bf16 gather ------------------
#define AGG_BLOCKS 3126
__global__ __launch_bounds__(256)
void k_gat_agg(const unsigned* __restrict__ hp2, const float* __restrict__ es,
               const float* __restrict__ ed, const int* __restrict__ row_ptr,
               const int* __restrict__ col_src, const float* __restrict__ bg,
               unsigned* __restrict__ hbf2){
  int lane = threadIdx.x & 63;
  int wav0 = blockIdx.x*4 + (threadIdx.x >> 6);
  const int NW = AGG_BLOCKS*4;
  float2 bgv = *(const float2*)&bg[2*lane];

  for (int i = wav0; i < N_NODES; i += NW){
    int start = row_ptr[i], end = row_ptr[i+1];
    float edi = ed[i];
    float m0 = leaky(es[i] + edi);              // self score: softmax recentering
    unsigned us = hp2[((unsigned)i<<6) | lane];
    float acc0 = bf_lo(us), acc1 = bf_hi(us);   // self weight exp(0)=1
    float zl = (lane==0) ? 1.f : 0.f;

    for (int c0 = start; c0 < end; c0 += 64){
      int j = c0 + lane;
      bool valid = j < end;
      int s = valid ? col_src[j] : 0;
      float e = leaky(es[s] + edi);
      float w = valid ? __expf(e - m0) : 0.f;
      zl += w;
      int len = end - c0; if (len > 64) len = 64;
      int t = 0;
      for (; t + 8 <= len; t += 8){
        unsigned o0=((unsigned)rl_i(s,t  )<<6)|lane, o1=((unsigned)rl_i(s,t+1)<<6)|lane;
        unsigned o2=((unsigned)rl_i(s,t+2)<<6)|lane, o3=((unsigned)rl_i(s,t+3)<<6)|lane;
        unsigned o4=((unsigned)rl_i(s,t+4)<<6)|lane, o5=((unsigned)rl_i(s,t+5)<<6)|lane;
        unsigned o6=((unsigned)rl_i(s,t+6)<<6)|lane, o7=((unsigned)rl_i(s,t+7)<<6)|lane;
        unsigned u0=hp2[o0], u1=hp2[o1], u2=hp2[o2], u3=hp2[o3];
        unsigned u4=hp2[o4], u5=hp2[o5], u6=hp2[o6], u7=hp2[o7];
        float w0=rl_f(w,t),   w1=rl_f(w,t+1), w2=rl_f(w,t+2), w3=rl_f(w,t+3);
        float w4=rl_f(w,t+4), w5=rl_f(w,t+5), w6=rl_f(w,t+6), w7=rl_f(w,t+7);
        acc0 = fmaf(w0, bf_lo(u0), acc0); acc1 = fmaf(w0, bf_hi(u0), acc1);
        acc0 = fmaf(w1, bf_lo(u1), acc0); acc1 = fmaf(w1, bf_hi(u1), acc1);
        acc0 = fmaf(w2, bf_lo(u2), acc0); acc1 = fmaf(w2, bf_hi(u2), acc1);
        acc0 = fmaf(w3, bf_lo(u3), acc0); acc1 = fmaf(w3, bf_hi(u3), acc1);
        acc0 = fmaf(w4, bf_lo(u4), acc0); acc1 = fmaf(w4, bf_hi(u4), acc1);
        acc0 = fmaf(w5, bf_lo(u5), acc0); acc1 = fmaf(w5, bf_hi(u5), acc1);
        acc0 = fmaf(w6, bf_lo(u6), acc0); acc1 = fmaf(w6, bf_hi(u6), acc1);
        acc0 = fmaf(w7, bf_lo(u7), acc0); acc1 = fmaf(w7, bf_hi(u7), acc1);
      }
      for (; t + 4 <= len; t += 4){
        unsigned o0=((unsigned)rl_i(s,t  )<<6)|lane, o1=((unsigned)rl_i(s,t+1)<<6)|lane;
        unsigned o2=((unsigned)rl_i(s,t+2)<<6)|lane, o3=((unsigned)rl_i(s,t+3)<<6)|lane;
        unsigned u0=hp2[o0], u1=hp2[o1], u2=hp2[o2], u3=hp2[o3];
        float w0=rl_f(w,t), w1=rl_f(w,t+1), w2=rl_f(w,t+2), w3=rl_f(w,t+3);
        acc0 = fmaf(w0, bf_lo(u0), acc0); acc1 = fmaf(w0, bf_hi(u0), acc1);
        acc0 = fmaf(w1, bf_lo(u1), acc0); acc1 = fmaf(w1, bf_hi(u1), acc1);
        acc0 = fmaf(w2, bf_lo(u2), acc0); acc1 = fmaf(w2, bf_hi(u2), acc1);
        acc0 = fmaf(w3, bf_lo(u3), acc0); acc1 = fmaf(w3, bf_hi(u3), acc1);
      }
      for (; t < len; t++){
        unsigned u = hp2[((unsigned)rl_i(s,t)<<6) | lane];
        float wt = rl_f(w,t);
        acc0 = fmaf(wt, bf_lo(u), acc0);
        acc1 = fmaf(wt, bf_hi(u), acc1);
      }
    }

    float z = zl;
    #pragma unroll
    for (int off=32; off>0; off>>=1) z += __shfl_xor(z, off, 64);
    float inv = 1.f / z;
    float r0 = fmaf(acc0, inv, bgv.x);
    float r1 = fmaf(acc1, inv, bgv.y);
    r0 = r0 > 0.f ? r0 : 0.f;
    r1 = r1 > 0.f ? r1 : 0.f;
    unsigned ho = hbf2[((unsigned)i<<6) | lane];   // residual (bf16 stream)
    hbf2[((unsigned)i<<6) | lane] = pack2bf(r0 + bf_lo(ho), r1 + bf_hi(ho));
  }
}

// ---------------- global_add_pool (batch sorted -> run accumulate), bf16 in ------------
__global__ __launch_bounds__(256)
void k_pool(const unsigned* __restrict__ hbf2, const int* __restrict__ batch,
            float* __restrict__ pooled){
  int lane = threadIdx.x & 63, w = threadIdx.x >> 6;
  int n0 = blockIdx.x*128 + w*32;
  if (n0 >= N_NODES) return;
  int nEnd = n0 + 32; if (nEnd > N_NODES) nEnd = N_NODES;
  int cur = batch[n0];
  float a0 = 0.f, a1 = 0.f;
  for (int n = n0; n < nEnd; n++){
    int b = batch[n];
    if (b != cur){
      atomicAdd(&pooled[cur*128 + 2*lane],     a0);
      atomicAdd(&pooled[cur*128 + 2*lane + 1], a1);
      a0 = 0.f; a1 = 0.f; cur = b;
    }
    unsigned u = hbf2[((unsigned)n<<6) | lane];
    a0 += bf_lo(u); a1 += bf_hi(u);
  }
  atomicAdd(&pooled[cur*128 + 2*lane],     a0);
  atomicAdd(&pooled[cur*128 + 2*lane + 1], a1);
}

__global__ void k_final(const float* __restrict__ pooled, const float* __restrict__ W2,
                        const float* __restrict__ b2, float* __restrict__ out){
  int gid = blockIdx.x*256 + threadIdx.x;
  if (gid >= NG*DOUT) return;
  int r = gid >> 6, c = gid & 63;
  float acc = b2[c];
  #pragma unroll 4
  for (int k=0;k<DH;k++) acc = fmaf(pooled[r*DH+k], W2[k*DOUT+c], acc);
  out[(size_t)r*DOUT + c] = acc;
}

extern "C" void kernel_launch(void* const* d_in, const int* in_sizes, int n_in,
                              void* d_out, int out_size, void* d_ws, size_t ws_size,
                              hipStream_t stream){
  const float* x     = (const float*)d_in[0];
  const int*   ei    = (const int*)d_in[1];
  const int*   batch = (const int*)d_in[2];
  const float* W1    = (const float*)d_in[3];
  const float* b1    = (const float*)d_in[4];
  const float* Wg    = (const float*)d_in[5];
  const float* avs   = (const float*)d_in[6];
  const float* avd   = (const float*)d_in[7];
  const float* bgv   = (const float*)d_in[8];
  const float* W2    = (const float*)d_in[9];
  const float* b2    = (const float*)d_in[10];
  float* out = (float*)d_out;

  char* ws = (char*)d_ws;
  unsigned short* hbf = (unsigned short*)ws;       ws += (size_t)N_NODES*DH*2;   // residual stream (bf16)
  unsigned short* hp  = (unsigned short*)ws;       ws += (size_t)N_NODES*DH*2;   // GEMM out (bf16)
  float* es       = (float*)ws;                    ws += (size_t)N_NODES*4;
  float* ed       = (float*)ws;                    ws += (size_t)N_NODES*4;
  float* pooled   = (float*)ws;                    ws += NG*DH*4;
  unsigned short* Wt = (unsigned short*)ws;        ws += 4*16384*2;
  int* counts     = (int*)ws;                      ws += (size_t)N_NODES*4;
  int* row_ptr    = (int*)ws;                      ws += ((size_t)N_NODES+1)*4;
  int* rank       = (int*)ws;                      ws += (size_t)N_EDGES*4;
  int* col_src    = (int*)ws;                      ws += (size_t)N_EDGES*4;
  int* bsum       = (int*)ws;                      ws += 64*4;

  const int* esrc = ei;
  const int* edst = ei + N_EDGES;

  hipMemsetAsync(counts, 0, N_NODES*sizeof(int), stream);
  hipMemsetAsync(pooled, 0, NG*DH*sizeof(float), stream);

  // K1: edge histogram + weight transpose/cast
  k_hist<<<1024, 256, 0, stream>>>(edst, counts, rank, W1, Wg, Wt);
  // K2: mlp1 GEMM (391 blocks) overlapped with scan phase-1 (25 blocks)
  k_lin1_scan1<<<LB + 25, 512, 0, stream>>>(x, Wt, b1, hbf, counts, bsum);
  // K3: scan phase-2+3 (only exposed CSR cost, ~4 us)
  k_bscan3<<<25, 256, 0, stream>>>(counts, bsum, row_ptr, 25);
  // K4: layer-0 GEMM + es/ed (391 blocks) overlapped with CSR scatter (633 blocks)
  k_lin_scatter<<<1024, 512, 0, stream>>>(hbf, Wt + 16384, avs, avd,
                                          hp, es, ed, esrc, edst, rank, row_ptr, col_src);
  // K5: layer-0 aggregation
  k_gat_agg<<<AGG_BLOCKS, 256, 0, stream>>>((const unsigned*)hp, es, ed,
                                            row_ptr, col_src, bgv, (unsigned*)hbf);
  // layers 1,2
  for (int l = 1; l < 3; l++){
    k_linear_mfma<false><<<LB, 512, 0, stream>>>(hbf, Wt + (size_t)(l+1)*16384, nullptr,
                                                 avs + l*DH, avd + l*DH,
                                                 hp, es, ed, N_NODES);
    k_gat_agg<<<AGG_BLOCKS, 256, 0, stream>>>((const unsigned*)hp, es, ed,
                                              row_ptr, col_src, bgv + l*DH,
                                              (unsigned*)hbf);
  }
  // K9: pool (391 blocks, run-accumulate, ~100k atomics) + K10: final linear
  k_pool<<<(N_NODES+127)/128, 256, 0, stream>>>((const unsigned*)hbf, batch, pooled);
  k_final<<<(NG*DOUT+255)/256, 256, 0, stream>>>(pooled, W2, b2, out);
}

// Round 3
// 294.514 us; speedup vs baseline: 1.1361x; 1.0221x over previous
//
#include <hip/hip_runtime.h>

#define N_NODES 50000
#define N_EDGES 600000
#define DH 128
#define DOUT 64
#define NG 64
#define SLOPE 0.2f
#define LB 391   // GEMM blocks: (N_NODES+127)/128

using short8  = __attribute__((ext_vector_type(8))) short;
using floatx4 = __attribute__((ext_vector_type(4))) float;

__device__ __forceinline__ float leaky(float v){ return fmaxf(v, SLOPE*v); }
__device__ __forceinline__ unsigned f2bf(float x){
  unsigned u = __float_as_uint(x);
  return (u + 0x7fffu + ((u>>16)&1u)) >> 16;          // RNE bf16
}
#if __has_builtin(__builtin_amdgcn_cvt_pk_bf16_f32)
__device__ __forceinline__ unsigned pack2bf(float a, float b){
  auto t = __builtin_amdgcn_cvt_pk_bf16_f32(a, b);
  unsigned u; __builtin_memcpy(&u, &t, 4); return u;
}
#else
__device__ __forceinline__ unsigned pack2bf(float a, float b){
  return f2bf(a) | (f2bf(b) << 16);
}
#endif
__device__ __forceinline__ float bf_lo(unsigned u){ return __uint_as_float(u<<16); }
__device__ __forceinline__ float bf_hi(unsigned u){ return __uint_as_float(u & 0xffff0000u); }

// ---------------- CSR build + weight prep ----------------------------------------------
// k_hist also performs the Wt transpose+cast (independent work riding one launch).
// NOTE (R1 lesson): do NOT fuse pool+final into one 64-block kernel — 2.2% occupancy,
// latency-bound, 64 us. k_pool's 391-block run-accumulation shape is the right one.
__global__ __launch_bounds__(256)
void k_hist(const int* __restrict__ dst, int* __restrict__ counts,
            int* __restrict__ rank,
            const float* __restrict__ W1, const float* __restrict__ Wg,
            unsigned short* __restrict__ Wt){
  int gid = blockIdx.x*256 + threadIdx.x;
  if (gid < 4*16384){                          // weight prep rides along
    int mi = gid >> 14, r = gid & 16383;
    int k = r >> 7, n = r & 127;
    const float* src = (mi==0) ? W1 : (Wg + (size_t)(mi-1)*16384);
    Wt[(size_t)mi*16384 + (size_t)n*128 + k] = (unsigned short)f2bf(src[k*128 + n]);
  }
  int stride = gridDim.x*256;
  for (int e = gid; e < N_EDGES; e += stride){
    rank[e] = atomicAdd(&counts[dst[e]], 1);
  }
}

// phase 2+3 fused: each block redundantly prefix-sums the nb block sums (<=25 adds),
// then does its local exclusive scan + propagate. (25 blocks, 256 threads)
__global__ __launch_bounds__(256)
void k_bscan3(const int* __restrict__ counts, const int* __restrict__ bsum,
              int* __restrict__ row_ptr, int nb){
  __shared__ int sb[256];
  __shared__ int sbs[64];
  int t = threadIdx.x;
  if (t < nb) sbs[t] = bsum[t];
  int base = blockIdx.x*2048;
  int c[8]; int s=0;
  #pragma unroll
  for (int j=0;j<8;j++){ int i = base+t*8+j; c[j] = (i<N_NODES)? counts[i]:0; s += c[j]; }
  sb[t]=s; __syncthreads();
  for (int off=1; off<256; off<<=1){
    int v = (t>=off)? sb[t-off] : 0;
    __syncthreads();
    sb[t]+=v;
    __syncthreads();
  }
  int boffv = 0;
  for (int b=0;b<(int)blockIdx.x;b++) boffv += sbs[b];
  int run = sb[t]-s + boffv;
  #pragma unroll
  for (int j=0;j<8;j++){
    int i = base+t*8+j;
    if (i<N_NODES){ row_ptr[i]=run; run+=c[j]; }
  }
  if ((int)blockIdx.x == nb-1 && t == 0){
    row_ptr[N_NODES] = boffv + sbs[nb-1];      // == N_EDGES
  }
}

// ---------------- MFMA GEMM body (transposed D): out[node][feat] bf16, fused es/ed -----
// 512 thr / 8 waves / 128 nodes per block. Wt: [n][k] bf16 staged in LDS (+8 pad).
// mfma(A=Wt frag, B=node frag): D[m=feature][n=node]; C/D: col(node)=lane&15,
// row(feature)=quad*4+reg -> each lane owns 4 CONSECUTIVE features per nt tile.
template<bool AFP32>
__device__ __forceinline__
void lin_body(const void* __restrict__ Av,
              const unsigned short* __restrict__ Wt,
              const float* __restrict__ bias,
              const float* __restrict__ avs, const float* __restrict__ avd,
              unsigned short* __restrict__ outB,
              float* __restrict__ es, float* __restrict__ ed, int nrows,
              int bid, unsigned short* wlds){
  int tid = threadIdx.x;
  #pragma unroll
  for (int i=0;i<4;i++){
    int flat = i*4096 + tid*8;
    int n = flat >> 7, kb = flat & 127;
    *(short8*)&wlds[n*136 + kb] = *(const short8*)(Wt + flat);
  }
  __syncthreads();

  int wid = tid >> 6, lane = tid & 63;
  int l15 = lane & 15, quad = lane >> 4;
  int R0 = bid*128 + wid*16;
  int node = R0 + l15;
  int arow = node < nrows ? node : nrows-1;

  floatx4 acc[8];
  #pragma unroll
  for (int nt=0;nt<8;nt++){ acc[nt][0]=0.f; acc[nt][1]=0.f; acc[nt][2]=0.f; acc[nt][3]=0.f; }

  #pragma unroll
  for (int k0=0;k0<128;k0+=32){
    short8 a;                                   // node fragment (B operand)
    if (AFP32){
      const float* Ap = (const float*)Av + (size_t)arow*128 + quad*8 + k0;
      float4 v0 = *(const float4*)Ap;
      float4 v1 = *(const float4*)(Ap+4);
      union { short8 s; unsigned u[4]; } cv;
      cv.u[0]=pack2bf(v0.x,v0.y); cv.u[1]=pack2bf(v0.z,v0.w);
      cv.u[2]=pack2bf(v1.x,v1.y); cv.u[3]=pack2bf(v1.z,v1.w);
      a = cv.s;
    } else {
      a = *(const short8*)((const unsigned short*)Av + (size_t)arow*128 + quad*8 + k0);
    }
    const unsigned short* bp = &wlds[l15*136 + quad*8 + k0];
    #pragma unroll
    for (int nt=0;nt<8;nt++){
      short8 b = *(const short8*)(bp + nt*16*136);   // Wt fragment (A operand)
      acc[nt] = __builtin_amdgcn_mfma_f32_16x16x32_bf16(b, a, acc[nt], 0,0,0);
    }
  }

  bool nv = node < nrows;
  float ps = 0.f, pd = 0.f;
  #pragma unroll
  for (int nt=0;nt<8;nt++){
    int f0 = nt*16 + quad*4;                  // 4 consecutive features for this lane
    float4 bb = make_float4(0.f,0.f,0.f,0.f);
    if (bias) bb = *(const float4*)(bias + f0);
    float v0 = acc[nt][0]+bb.x, v1 = acc[nt][1]+bb.y;
    float v2 = acc[nt][2]+bb.z, v3 = acc[nt][3]+bb.w;
    if (es){
      float4 a4 = *(const float4*)(avs + f0);
      float4 d4 = *(const float4*)(avd + f0);
      ps = fmaf(v0,a4.x, fmaf(v1,a4.y, fmaf(v2,a4.z, fmaf(v3,a4.w, ps))));
      pd = fmaf(v0,d4.x, fmaf(v1,d4.y, fmaf(v2,d4.z, fmaf(v3,d4.w, pd))));
    }
    if (nv){
      uint2 pk; pk.x = pack2bf(v0,v1); pk.y = pack2bf(v2,v3);
      *(uint2*)(outB + (size_t)node*128 + f0) = pk;
    }
  }
  if (es){
    ps += __shfl_xor(ps, 16, 64); ps += __shfl_xor(ps, 32, 64);
    pd += __shfl_xor(pd, 16, 64); pd += __shfl_xor(pd, 32, 64);
    if (quad==0 && nv){ es[node]=ps; ed[node]=pd; }
  }
}

template<bool AFP32>
__global__ __launch_bounds__(512)
void k_linear_mfma(const void* __restrict__ Av,
                   const unsigned short* __restrict__ Wt,
                   const float* __restrict__ bias,
                   const float* __restrict__ avs, const float* __restrict__ avd,
                   unsigned short* __restrict__ outB,
                   float* __restrict__ es, float* __restrict__ ed, int nrows){
  __shared__ unsigned short wlds[128*136];
  lin_body<AFP32>(Av, Wt, bias, avs, avd, outB, es, ed, nrows, blockIdx.x, wlds);
}

// ---------------- fat kernel: mlp1 GEMM (blocks <LB) ∥ scan phase-1 (blocks >=LB) ------
__global__ __launch_bounds__(512)
void k_lin1_scan1(const float* __restrict__ x, const unsigned short* __restrict__ Wt,
                  const float* __restrict__ b1, unsigned short* __restrict__ hbf,
                  const int* __restrict__ counts, int* __restrict__ bsum){
  if ((int)blockIdx.x >= LB){
    __shared__ int sb1[512];
    int sbid = blockIdx.x - LB;
    int base = sbid*2048;
    int t = threadIdx.x;
    int s = 0;
    #pragma unroll
    for (int j=0;j<4;j++){ int i = base + t*4 + j; if (i < N_NODES) s += counts[i]; }
    sb1[t]=s; __syncthreads();
    for (int off=256; off>0; off>>=1){ if (t<off) sb1[t]+=sb1[t+off]; __syncthreads(); }
    if (t==0) bsum[sbid]=sb1[0];
    return;
  }
  __shared__ unsigned short wlds[128*136];
  lin_body<true>(x, Wt, b1, nullptr, nullptr, hbf, nullptr, nullptr, N_NODES,
                 blockIdx.x, wlds);
}

// ---------------- fat kernel: layer-0 GEMM (blocks <LB) ∥ CSR scatter (blocks >=LB) ----
__global__ __launch_bounds__(512)
void k_lin_scatter(const unsigned short* __restrict__ hbf,
                   const unsigned short* __restrict__ Wt,
                   const float* __restrict__ avs, const float* __restrict__ avd,
                   unsigned short* __restrict__ hp,
                   float* __restrict__ es, float* __restrict__ ed,
                   const int* __restrict__ esrc, const int* __restrict__ edst,
                   const int* __restrict__ rank, const int* __restrict__ row_ptr,
                   int* __restrict__ col_src){
  if ((int)blockIdx.x >= LB){
    int e0 = (blockIdx.x - LB)*512 + threadIdx.x;
    const int stride = (1024 - LB)*512;
    for (int e = e0; e < N_EDGES; e += stride){
      col_src[row_ptr[edst[e]] + rank[e]] = esrc[e];
    }
    return;
  }
  __shared__ unsigned short wlds[128*136];
  lin_body<false>(hbf, Wt, nullptr, avs, avd, hp, es, ed, N_NODES, blockIdx.x, wlds);
}

// ---------------- GAT aggregation: 4-edges-per-VMEM gather ----------------------------
// R2 redesign: quad q (lane>>4) owns edge t+q; each lane loads dwordx4 (16B = 8 features)
// -> one VMEM instruction fetches 4 edge-rows (1KB). s/w broadcast via __shfl (bpermute,
// LDS pipe). acc[8] per lane (features sub*8..+7), cross-quad shfl_xor reduce at end.
#define AGG_BLOCKS 3126
__global__ __launch_bounds__(256)
void k_gat_agg(const unsigned* __restrict__ hp2, const float* __restrict__ es,
               const float* __restrict__ ed, const int* __restrict__ row_ptr,
               const int* __restrict__ col_src, const float* __restrict__ bg,
               unsigned* __restrict__ hbf2){
  int lane = threadIdx.x & 63;
  int sub = lane & 15, quad = lane >> 4;
  int subw = sub << 2;                          // word offset of this lane's 16B chunk
  int wav0 = blockIdx.x*4 + (threadIdx.x >> 6);
  const int NW = AGG_BLOCKS*4;

  for (int i = wav0; i < N_NODES; i += NW){
    int start = row_ptr[i], end = row_ptr[i+1];
    float edi = ed[i];
    float m0 = leaky(es[i] + edi);              // self score: softmax recentering
    float acc[8];
    if (quad == 0){                             // self weight exp(0)=1, quad0 only
      uint4 u = *(const uint4*)(hp2 + (((unsigned)i<<6) | subw));
      acc[0]=bf_lo(u.x); acc[1]=bf_hi(u.x); acc[2]=bf_lo(u.y); acc[3]=bf_hi(u.y);
      acc[4]=bf_lo(u.z); acc[5]=bf_hi(u.z); acc[6]=bf_lo(u.w); acc[7]=bf_hi(u.w);
    } else {
      #pragma unroll
      for (int r=0;r<8;r++) acc[r]=0.f;
    }
    float zl = (lane==0) ? 1.f : 0.f;

    for (int c0 = start; c0 < end; c0 += 64){
      int j = c0 + lane;
      bool valid = j < end;
      int sreg = valid ? col_src[j] : 0;
      float e = leaky(es[sreg] + edi);
      float w = valid ? __expf(e - m0) : 0.f;   // invalid lanes: w=0 (safe in groups)
      zl += w;
      int len = end - c0; if (len > 64) len = 64;
      int lenp = (len + 3) & ~3;                // round up to whole groups of 4
      int t = 0;
      for (; t + 8 <= lenp; t += 8){            // 2 groups in flight (2KB/wave)
        int iA = t + quad,          iB = t + 4 + quad;
        int   sA = __shfl(sreg, iA, 64),  sB = __shfl(sreg, iB, 64);
        float wA = __shfl(w,    iA, 64),  wB = __shfl(w,    iB, 64);
        uint4 uA = *(const uint4*)(hp2 + (((unsigned)sA<<6) | subw));
        uint4 uB = *(const uint4*)(hp2 + (((unsigned)sB<<6) | subw));
        acc[0]=fmaf(wA, bf_lo(uA.x), acc[0]); acc[1]=fmaf(wA, bf_hi(uA.x), acc[1]);
        acc[2]=fmaf(wA, bf_lo(uA.y), acc[2]); acc[3]=fmaf(wA, bf_hi(uA.y), acc[3]);
        acc[4]=fmaf(wA, bf_lo(uA.z), acc[4]); acc[5]=fmaf(wA, bf_hi(uA.z), acc[5]);
        acc[6]=fmaf(wA, bf_lo(uA.w), acc[6]); acc[7]=fmaf(wA, bf_hi(uA.w), acc[7]);
        acc[0]=fmaf(wB, bf_lo(uB.x), acc[0]); acc[1]=fmaf(wB, bf_hi(uB.x), acc[1]);
        acc[2]=fmaf(wB, bf_lo(uB.y), acc[2]); acc[3]=fmaf(wB, bf_hi(uB.y), acc[3]);
        acc[4]=fmaf(wB, bf_lo(uB.z), acc[4]); acc[5]=fmaf(wB, bf_hi(uB.z), acc[5]);
        acc[6]=fmaf(wB, bf_lo(uB.w), acc[6]); acc[7]=fmaf(wB, bf_hi(uB.w), acc[7]);
      }
      if (t < lenp){
        int iA = t + quad;
        int   sA = __shfl(sreg, iA, 64);
        float wA = __shfl(w,    iA, 64);
        uint4 uA = *(const uint4*)(hp2 + (((unsigned)sA<<6) | subw));
        acc[0]=fmaf(wA, bf_lo(uA.x), acc[0]); acc[1]=fmaf(wA, bf_hi(uA.x), acc[1]);
        acc[2]=fmaf(wA, bf_lo(uA.y), acc[2]); acc[3]=fmaf(wA, bf_hi(uA.y), acc[3]);
        acc[4]=fmaf(wA, bf_lo(uA.z), acc[4]); acc[5]=fmaf(wA, bf_hi(uA.z), acc[5]);
        acc[6]=fmaf(wA, bf_lo(uA.w), acc[6]); acc[7]=fmaf(wA, bf_hi(uA.w), acc[7]);
      }
    }

    // cross-quad reduce: 4 edge-slots accumulated the same feature set
    #pragma unroll
    for (int r=0;r<8;r++){
      acc[r] += __shfl_xor(acc[r], 16, 64);
      acc[r] += __shfl_xor(acc[r], 32, 64);
    }
    float z = zl;
    #pragma unroll
    for (int off=32; off>0; off>>=1) z += __shfl_xor(z, off, 64);
    float inv = 1.f / z;

    if (quad == 0){
      float4 bgA = *(const float4*)(bg + sub*8);
      float4 bgB = *(const float4*)(bg + sub*8 + 4);
      unsigned base = ((unsigned)i<<6) | subw;
      uint4 ho = *(const uint4*)(hbf2 + base);   // residual (bf16 stream)
      float r0 = fmaf(acc[0], inv, bgA.x); r0 = r0>0.f?r0:0.f; r0 += bf_lo(ho.x);
      float r1 = fmaf(acc[1], inv, bgA.y); r1 = r1>0.f?r1:0.f; r1 += bf_hi(ho.x);
      float r2 = fmaf(acc[2], inv, bgA.z); r2 = r2>0.f?r2:0.f; r2 += bf_lo(ho.y);
      float r3 = fmaf(acc[3], inv, bgA.w); r3 = r3>0.f?r3:0.f; r3 += bf_hi(ho.y);
      float r4 = fmaf(acc[4], inv, bgB.x); r4 = r4>0.f?r4:0.f; r4 += bf_lo(ho.z);
      float r5 = fmaf(acc[5], inv, bgB.y); r5 = r5>0.f?r5:0.f; r5 += bf_hi(ho.z);
      float r6 = fmaf(acc[6], inv, bgB.z); r6 = r6>0.f?r6:0.f; r6 += bf_lo(ho.w);
      float r7 = fmaf(acc[7], inv, bgB.w); r7 = r7>0.f?r7:0.f; r7 += bf_hi(ho.w);
      uint4 pk;
      pk.x = pack2bf(r0,r1); pk.y = pack2bf(r2,r3);
      pk.z = pack2bf(r4,r5); pk.w = pack2bf(r6,r7);
      *(uint4*)(hbf2 + base) = pk;
    }
  }
}

// ---------------- global_add_pool (batch sorted -> run accumulate), bf16 in ------------
__global__ __launch_bounds__(256)
void k_pool(const unsigned* __restrict__ hbf2, const int* __restrict__ batch,
            float* __restrict__ pooled){
  int lane = threadIdx.x & 63, w = threadIdx.x >> 6;
  int n0 = blockIdx.x*128 + w*32;
  if (n0 >= N_NODES) return;
  int nEnd = n0 + 32; if (nEnd > N_NODES) nEnd = N_NODES;
  int cur = batch[n0];
  float a0 = 0.f, a1 = 0.f;
  for (int n = n0; n < nEnd; n++){
    int b = batch[n];
    if (b != cur){
      atomicAdd(&pooled[cur*128 + 2*lane],     a0);
      atomicAdd(&pooled[cur*128 + 2*lane + 1], a1);
      a0 = 0.f; a1 = 0.f; cur = b;
    }
    unsigned u = hbf2[((unsigned)n<<6) | lane];
    a0 += bf_lo(u); a1 += bf_hi(u);
  }
  atomicAdd(&pooled[cur*128 + 2*lane],     a0);
  atomicAdd(&pooled[cur*128 + 2*lane + 1], a1);
}

__global__ void k_final(const float* __restrict__ pooled, const float* __restrict__ W2,
                        const float* __restrict__ b2, float* __restrict__ out){
  int gid = blockIdx.x*256 + threadIdx.x;
  if (gid >= NG*DOUT) return;
  int r = gid >> 6, c = gid & 63;
  float acc = b2[c];
  #pragma unroll 4
  for (int k=0;k<DH;k++) acc = fmaf(pooled[r*DH+k], W2[k*DOUT+c], acc);
  out[(size_t)r*DOUT + c] = acc;
}

extern "C" void kernel_launch(void* const* d_in, const int* in_sizes, int n_in,
                              void* d_out, int out_size, void* d_ws, size_t ws_size,
                              hipStream_t stream){
  const float* x     = (const float*)d_in[0];
  const int*   ei    = (const int*)d_in[1];
  const int*   batch = (const int*)d_in[2];
  const float* W1    = (const float*)d_in[3];
  const float* b1    = (const float*)d_in[4];
  const float* Wg    = (const float*)d_in[5];
  const float* avs   = (const float*)d_in[6];
  const float* avd   = (const float*)d_in[7];
  const float* bgv   = (const float*)d_in[8];
  const float* W2    = (const float*)d_in[9];
  const float* b2    = (const float*)d_in[10];
  float* out = (float*)d_out;

  char* ws = (char*)d_ws;
  unsigned short* hbf = (unsigned short*)ws;       ws += (size_t)N_NODES*DH*2;   // residual stream (bf16)
  unsigned short* hp  = (unsigned short*)ws;       ws += (size_t)N_NODES*DH*2;   // GEMM out (bf16)
  float* es       = (float*)ws;                    ws += (size_t)N_NODES*4;
  float* ed       = (float*)ws;                    ws += (size_t)N_NODES*4;
  float* pooled   = (float*)ws;                    ws += NG*DH*4;
  unsigned short* Wt = (unsigned short*)ws;        ws += 4*16384*2;
  int* counts     = (int*)ws;                      ws += (size_t)N_NODES*4;
  int* row_ptr    = (int*)ws;                      ws += ((size_t)N_NODES+1)*4;
  int* rank       = (int*)ws;                      ws += (size_t)N_EDGES*4;
  int* col_src    = (int*)ws;                      ws += (size_t)N_EDGES*4;
  int* bsum       = (int*)ws;                      ws += 64*4;

  const int* esrc = ei;
  const int* edst = ei + N_EDGES;

  hipMemsetAsync(counts, 0, N_NODES*sizeof(int), stream);
  hipMemsetAsync(pooled, 0, NG*DH*sizeof(float), stream);

  // K1: edge histogram + weight transpose/cast
  k_hist<<<1024, 256, 0, stream>>>(edst, counts, rank, W1, Wg, Wt);
  // K2: mlp1 GEMM (391 blocks) overlapped with scan phase-1 (25 blocks)
  k_lin1_scan1<<<LB + 25, 512, 0, stream>>>(x, Wt, b1, hbf, counts, bsum);
  // K3: scan phase-2+3 (only exposed CSR cost, ~4 us)
  k_bscan3<<<25, 256, 0, stream>>>(counts, bsum, row_ptr, 25);
  // K4: layer-0 GEMM + es/ed (391 blocks) overlapped with CSR scatter (633 blocks)
  k_lin_scatter<<<1024, 512, 0, stream>>>(hbf, Wt + 16384, avs, avd,
                                          hp, es, ed, esrc, edst, rank, row_ptr, col_src);
  // K5: layer-0 aggregation
  k_gat_agg<<<AGG_BLOCKS, 256, 0, stream>>>((const unsigned*)hp, es, ed,
                                            row_ptr, col_src, bgv, (unsigned*)hbf);
  // layers 1,2
  for (int l = 1; l < 3; l++){
    k_linear_mfma<false><<<LB, 512, 0, stream>>>(hbf, Wt + (size_t)(l+1)*16384, nullptr,
                                                 avs + l*DH, avd + l*DH,
                                                 hp, es, ed, N_NODES);
    k_gat_agg<<<AGG_BLOCKS, 256, 0, stream>>>((const unsigned*)hp, es, ed,
                                              row_ptr, col_src, bgv + l*DH,
                                              (unsigned*)hbf);
  }
  // K9: pool (391 blocks, run-accumulate, ~100k atomics) + K10: final linear
  k_pool<<<(N_NODES+127)/128, 256, 0, stream>>>((const unsigned*)hbf, batch, pooled);
  k_final<<<(NG*DOUT+255)/256, 256, 0, stream>>>(pooled, W2, b2, out);
}

// Round 4
// 288.707 us; speedup vs baseline: 1.1590x; 1.0201x over previous
//
#include <hip/hip_runtime.h>

#define N_NODES 50000
#define N_EDGES 600000
#define DH 128
#define DOUT 64
#define NG 64
#define SLOPE 0.2f
#define LB 391   // GEMM blocks: (N_NODES+127)/128
#define SCAN_BLOCKS 25

using short8  = __attribute__((ext_vector_type(8))) short;
using floatx4 = __attribute__((ext_vector_type(4))) float;

__device__ __forceinline__ float leaky(float v){ return fmaxf(v, SLOPE*v); }
__device__ __forceinline__ unsigned f2bf(float x){
  unsigned u = __float_as_uint(x);
  return (u + 0x7fffu + ((u>>16)&1u)) >> 16;          // RNE bf16
}
#if __has_builtin(__builtin_amdgcn_cvt_pk_bf16_f32)
__device__ __forceinline__ unsigned pack2bf(float a, float b){
  auto t = __builtin_amdgcn_cvt_pk_bf16_f32(a, b);
  unsigned u; __builtin_memcpy(&u, &t, 4); return u;
}
#else
__device__ __forceinline__ unsigned pack2bf(float a, float b){
  return f2bf(a) | (f2bf(b) << 16);
}
#endif
__device__ __forceinline__ float bf_lo(unsigned u){ return __uint_as_float(u<<16); }
__device__ __forceinline__ float bf_hi(unsigned u){ return __uint_as_float(u & 0xffff0000u); }
__device__ __forceinline__ int ld_acq(int* p){
  return __hip_atomic_load(p, __ATOMIC_ACQUIRE, __HIP_MEMORY_SCOPE_AGENT);
}
__device__ __forceinline__ void st_rel(int* p, int v){
  __hip_atomic_store(p, v, __ATOMIC_RELEASE, __HIP_MEMORY_SCOPE_AGENT);
}

// ---------------- CSR build + weight prep + pooled zero --------------------------------
// k_hist also performs the Wt transpose+cast and zeroes `pooled` (independent work).
// NOTE (R1 lesson): do NOT fuse pool+final into one 64-block kernel — 2.2% occupancy,
// latency-bound, 64 us. k_pool's 391-block run-accumulation shape is the right one.
__global__ __launch_bounds__(256)
void k_hist(const int* __restrict__ dst, int* __restrict__ counts,
            int* __restrict__ rank,
            const float* __restrict__ W1, const float* __restrict__ Wg,
            unsigned short* __restrict__ Wt, float* __restrict__ pooled){
  int gid = blockIdx.x*256 + threadIdx.x;
  if (gid < 4*16384){                          // weight prep rides along
    int mi = gid >> 14, r = gid & 16383;
    int k = r >> 7, n = r & 127;
    const float* src = (mi==0) ? W1 : (Wg + (size_t)(mi-1)*16384);
    Wt[(size_t)mi*16384 + (size_t)n*128 + k] = (unsigned short)f2bf(src[k*128 + n]);
  }
  if (gid < NG*DH) pooled[gid] = 0.f;          // pool accumulator zero rides along
  int stride = gridDim.x*256;
  for (int e = gid; e < N_EDGES; e += stride){
    rank[e] = atomicAdd(&counts[dst[e]], 1);
  }
}

// ---------------- MFMA GEMM body (transposed D): out[node][feat] bf16, fused es/ed -----
// 512 thr / 8 waves / 128 nodes per block. Wt: [n][k] bf16 staged in LDS (+8 pad).
// mfma(A=Wt frag, B=node frag): D[m=feature][n=node]; C/D: col(node)=lane&15,
// row(feature)=quad*4+reg -> each lane owns 4 CONSECUTIVE features per nt tile.
template<bool AFP32>
__device__ __forceinline__
void lin_body(const void* __restrict__ Av,
              const unsigned short* __restrict__ Wt,
              const float* __restrict__ bias,
              const float* __restrict__ avs, const float* __restrict__ avd,
              unsigned short* __restrict__ outB,
              float* __restrict__ es, float* __restrict__ ed, int nrows,
              int bid, unsigned short* wlds){
  int tid = threadIdx.x;
  #pragma unroll
  for (int i=0;i<4;i++){
    int flat = i*4096 + tid*8;
    int n = flat >> 7, kb = flat & 127;
    *(short8*)&wlds[n*136 + kb] = *(const short8*)(Wt + flat);
  }
  __syncthreads();

  int wid = tid >> 6, lane = tid & 63;
  int l15 = lane & 15, quad = lane >> 4;
  int R0 = bid*128 + wid*16;
  int node = R0 + l15;
  int arow = node < nrows ? node : nrows-1;

  floatx4 acc[8];
  #pragma unroll
  for (int nt=0;nt<8;nt++){ acc[nt][0]=0.f; acc[nt][1]=0.f; acc[nt][2]=0.f; acc[nt][3]=0.f; }

  #pragma unroll
  for (int k0=0;k0<128;k0+=32){
    short8 a;                                   // node fragment (B operand)
    if (AFP32){
      const float* Ap = (const float*)Av + (size_t)arow*128 + quad*8 + k0;
      float4 v0 = *(const float4*)Ap;
      float4 v1 = *(const float4*)(Ap+4);
      union { short8 s; unsigned u[4]; } cv;
      cv.u[0]=pack2bf(v0.x,v0.y); cv.u[1]=pack2bf(v0.z,v0.w);
      cv.u[2]=pack2bf(v1.x,v1.y); cv.u[3]=pack2bf(v1.z,v1.w);
      a = cv.s;
    } else {
      a = *(const short8*)((const unsigned short*)Av + (size_t)arow*128 + quad*8 + k0);
    }
    const unsigned short* bp = &wlds[l15*136 + quad*8 + k0];
    #pragma unroll
    for (int nt=0;nt<8;nt++){
      short8 b = *(const short8*)(bp + nt*16*136);   // Wt fragment (A operand)
      acc[nt] = __builtin_amdgcn_mfma_f32_16x16x32_bf16(b, a, acc[nt], 0,0,0);
    }
  }

  bool nv = node < nrows;
  float ps = 0.f, pd = 0.f;
  #pragma unroll
  for (int nt=0;nt<8;nt++){
    int f0 = nt*16 + quad*4;                  // 4 consecutive features for this lane
    float4 bb = make_float4(0.f,0.f,0.f,0.f);
    if (bias) bb = *(const float4*)(bias + f0);
    float v0 = acc[nt][0]+bb.x, v1 = acc[nt][1]+bb.y;
    float v2 = acc[nt][2]+bb.z, v3 = acc[nt][3]+bb.w;
    if (es){
      float4 a4 = *(const float4*)(avs + f0);
      float4 d4 = *(const float4*)(avd + f0);
      ps = fmaf(v0,a4.x, fmaf(v1,a4.y, fmaf(v2,a4.z, fmaf(v3,a4.w, ps))));
      pd = fmaf(v0,d4.x, fmaf(v1,d4.y, fmaf(v2,d4.z, fmaf(v3,d4.w, pd))));
    }
    if (nv){
      uint2 pk; pk.x = pack2bf(v0,v1); pk.y = pack2bf(v2,v3);
      *(uint2*)(outB + (size_t)node*128 + f0) = pk;
    }
  }
  if (es){
    ps += __shfl_xor(ps, 16, 64); ps += __shfl_xor(ps, 32, 64);
    pd += __shfl_xor(pd, 16, 64); pd += __shfl_xor(pd, 32, 64);
    if (quad==0 && nv){ es[node]=ps; ed[node]=pd; }
  }
}

template<bool AFP32>
__global__ __launch_bounds__(512)
void k_linear_mfma(const void* __restrict__ Av,
                   const unsigned short* __restrict__ Wt,
                   const float* __restrict__ bias,
                   const float* __restrict__ avs, const float* __restrict__ avd,
                   unsigned short* __restrict__ outB,
                   float* __restrict__ es, float* __restrict__ ed, int nrows){
  __shared__ unsigned short wlds[128*136];
  lin_body<AFP32>(Av, Wt, bias, avs, avd, outB, es, ed, nrows, blockIdx.x, wlds);
}

// ---------------- fat kernel: mlp1 GEMM (blocks <LB) ∥ FULL row_ptr scan (>=LB) --------
// Companion blocks do the complete exclusive scan via decoupled lookback over 25 scan
// blocks: local shared scan -> publish aggregate (release, flag=S+1) -> spin-read lower
// block aggregates (dispatched earlier; in-order dispatch => deadlock-free) -> write.
// Removes the separate k_bscan1/k_bscan3 dispatches entirely.
__global__ __launch_bounds__(512)
void k_lin1_scan(const float* __restrict__ x, const unsigned short* __restrict__ Wt,
                 const float* __restrict__ b1, unsigned short* __restrict__ hbf,
                 const int* __restrict__ counts, int* __restrict__ bsum,
                 int* __restrict__ row_ptr){
  __shared__ unsigned short wlds[128*136];
  if ((int)blockIdx.x >= LB){
    int* sb1 = (int*)wlds;          // reuse GEMM LDS: 512 ints scan + 33 ints lookback
    int* lk  = sb1 + 512;
    int sbid = blockIdx.x - LB;     // 0..24
    int t = threadIdx.x;
    int base = sbid*2048;
    int c[4]; int s=0;
    int idx0 = base + t*4;
    #pragma unroll
    for (int j=0;j<4;j++){ int idx = idx0+j; c[j] = (idx<N_NODES)? counts[idx]:0; s += c[j]; }
    sb1[t]=s; __syncthreads();
    for (int off=1; off<512; off<<=1){
      int v = (t>=off)? sb1[t-off] : 0;
      __syncthreads();
      sb1[t]+=v;
      __syncthreads();
    }
    int pre   = sb1[t]-s;           // exclusive prefix within this scan block
    int total = sb1[511];           // block aggregate
    if (t==0){ __threadfence(); st_rel(&bsum[sbid], total+1); }   // publish (flag: +1)
    int lv = 0;
    if (t < sbid){                  // lookback: spin on lower-indexed aggregates
      int v;
      do { v = ld_acq(&bsum[t]); } while (v == 0);
      lv = v - 1;
    }
    if (t < 32) lk[t] = lv;
    __syncthreads();
    if (t==0){ int b=0; for (int q=0;q<sbid;q++) b += lk[q]; lk[32]=b; }
    __syncthreads();
    int boff = lk[32];
    int run = pre + boff;
    #pragma unroll
    for (int j=0;j<4;j++){
      int idx = idx0+j;
      if (idx < N_NODES){ row_ptr[idx] = run; run += c[j]; }
    }
    if (sbid == SCAN_BLOCKS-1 && t == 0) row_ptr[N_NODES] = boff + total;  // == N_EDGES
    return;
  }
  lin_body<true>(x, Wt, b1, nullptr, nullptr, hbf, nullptr, nullptr, N_NODES,
                 blockIdx.x, wlds);
}

// ---------------- fat kernel: layer-0 GEMM (blocks <LB) ∥ CSR scatter (blocks >=LB) ----
__global__ __launch_bounds__(512)
void k_lin_scatter(const unsigned short* __restrict__ hbf,
                   const unsigned short* __restrict__ Wt,
                   const float* __restrict__ avs, const float* __restrict__ avd,
                   unsigned short* __restrict__ hp,
                   float* __restrict__ es, float* __restrict__ ed,
                   const int* __restrict__ esrc, const int* __restrict__ edst,
                   const int* __restrict__ rank, const int* __restrict__ row_ptr,
                   int* __restrict__ col_src){
  if ((int)blockIdx.x >= LB){
    int e0 = (blockIdx.x - LB)*512 + threadIdx.x;
    const int stride = (1024 - LB)*512;
    for (int e = e0; e < N_EDGES; e += stride){
      col_src[row_ptr[edst[e]] + rank[e]] = esrc[e];
    }
    return;
  }
  __shared__ unsigned short wlds[128*136];
  lin_body<false>(hbf, Wt, nullptr, avs, avd, hp, es, ed, N_NODES, blockIdx.x, wlds);
}

// ---------------- GAT aggregation: 4-edges-per-VMEM gather + cross-node prefetch -------
// quad q (lane>>4) owns edge t+q; each lane loads dwordx4 (16B = 8 features) -> one VMEM
// instruction fetches 4 edge-rows (1KB). s/w broadcast via __shfl. acc[8] per lane,
// cross-quad shfl_xor reduce. R4: next node's row_ptr/es/ed prefetched under the gather
// loop (cuts one ~400cyc dependent chain per node; scalar-only to stay under 64 VGPR).
#define AGG_BLOCKS 3126
__global__ __launch_bounds__(256)
void k_gat_agg(const unsigned* __restrict__ hp2, const float* __restrict__ es,
               const float* __restrict__ ed, const int* __restrict__ row_ptr,
               const int* __restrict__ col_src, const float* __restrict__ bg,
               unsigned* __restrict__ hbf2){
  int lane = threadIdx.x & 63;
  int sub = lane & 15, quad = lane >> 4;
  int subw = sub << 2;                          // word offset of this lane's 16B chunk
  int wav0 = blockIdx.x*4 + (threadIdx.x >> 6);
  const int NW = AGG_BLOCKS*4;

  int i = wav0;
  int start=0, end=0; float esi=0.f, edi=0.f;
  if (i < N_NODES){
    start = row_ptr[i]; end = row_ptr[i+1];
    esi = es[i]; edi = ed[i];
  }
  while (i < N_NODES){
    int inext = i + NW;
    int nstart=0, nend=0; float nes=0.f, ned=0.f;
    if (inext < N_NODES){                       // prefetch next node's scalars
      nstart = row_ptr[inext]; nend = row_ptr[inext+1];
      nes = es[inext]; ned = ed[inext];
    }
    float m0 = leaky(esi + edi);                // self score: softmax recentering
    float acc[8];
    if (quad == 0){                             // self weight exp(0)=1, quad0 only
      uint4 u = *(const uint4*)(hp2 + (((unsigned)i<<6) | subw));
      acc[0]=bf_lo(u.x); acc[1]=bf_hi(u.x); acc[2]=bf_lo(u.y); acc[3]=bf_hi(u.y);
      acc[4]=bf_lo(u.z); acc[5]=bf_hi(u.z); acc[6]=bf_lo(u.w); acc[7]=bf_hi(u.w);
    } else {
      #pragma unroll
      for (int r=0;r<8;r++) acc[r]=0.f;
    }
    float zl = (lane==0) ? 1.f : 0.f;

    for (int c0 = start; c0 < end; c0 += 64){
      int j = c0 + lane;
      bool valid = j < end;
      int sreg = valid ? col_src[j] : 0;
      float e = leaky(es[sreg] + edi);
      float w = valid ? __expf(e - m0) : 0.f;   // invalid lanes: w=0 (safe in groups)
      zl += w;
      int len = end - c0; if (len > 64) len = 64;
      int lenp = (len + 3) & ~3;                // round up to whole groups of 4
      int t = 0;
      for (; t + 8 <= lenp; t += 8){            // 2 groups in flight (2KB/wave)
        int iA = t + quad,          iB = t + 4 + quad;
        int   sA = __shfl(sreg, iA, 64),  sB = __shfl(sreg, iB, 64);
        float wA = __shfl(w,    iA, 64),  wB = __shfl(w,    iB, 64);
        uint4 uA = *(const uint4*)(hp2 + (((unsigned)sA<<6) | subw));
        uint4 uB = *(const uint4*)(hp2 + (((unsigned)sB<<6) | subw));
        acc[0]=fmaf(wA, bf_lo(uA.x), acc[0]); acc[1]=fmaf(wA, bf_hi(uA.x), acc[1]);
        acc[2]=fmaf(wA, bf_lo(uA.y), acc[2]); acc[3]=fmaf(wA, bf_hi(uA.y), acc[3]);
        acc[4]=fmaf(wA, bf_lo(uA.z), acc[4]); acc[5]=fmaf(wA, bf_hi(uA.z), acc[5]);
        acc[6]=fmaf(wA, bf_lo(uA.w), acc[6]); acc[7]=fmaf(wA, bf_hi(uA.w), acc[7]);
        acc[0]=fmaf(wB, bf_lo(uB.x), acc[0]); acc[1]=fmaf(wB, bf_hi(uB.x), acc[1]);
        acc[2]=fmaf(wB, bf_lo(uB.y), acc[2]); acc[3]=fmaf(wB, bf_hi(uB.y), acc[3]);
        acc[4]=fmaf(wB, bf_lo(uB.z), acc[4]); acc[5]=fmaf(wB, bf_hi(uB.z), acc[5]);
        acc[6]=fmaf(wB, bf_lo(uB.w), acc[6]); acc[7]=fmaf(wB, bf_hi(uB.w), acc[7]);
      }
      if (t < lenp){
        int iA = t + quad;
        int   sA = __shfl(sreg, iA, 64);
        float wA = __shfl(w,    iA, 64);
        uint4 uA = *(const uint4*)(hp2 + (((unsigned)sA<<6) | subw));
        acc[0]=fmaf(wA, bf_lo(uA.x), acc[0]); acc[1]=fmaf(wA, bf_hi(uA.x), acc[1]);
        acc[2]=fmaf(wA, bf_lo(uA.y), acc[2]); acc[3]=fmaf(wA, bf_hi(uA.y), acc[3]);
        acc[4]=fmaf(wA, bf_lo(uA.z), acc[4]); acc[5]=fmaf(wA, bf_hi(uA.z), acc[5]);
        acc[6]=fmaf(wA, bf_lo(uA.w), acc[6]); acc[7]=fmaf(wA, bf_hi(uA.w), acc[7]);
      }
    }

    // cross-quad reduce: 4 edge-slots accumulated the same feature set
    #pragma unroll
    for (int r=0;r<8;r++){
      acc[r] += __shfl_xor(acc[r], 16, 64);
      acc[r] += __shfl_xor(acc[r], 32, 64);
    }
    float z = zl;
    #pragma unroll
    for (int off=32; off>0; off>>=1) z += __shfl_xor(z, off, 64);
    float inv = 1.f / z;

    if (quad == 0){
      float4 bgA = *(const float4*)(bg + sub*8);
      float4 bgB = *(const float4*)(bg + sub*8 + 4);
      unsigned base = ((unsigned)i<<6) | subw;
      uint4 ho = *(const uint4*)(hbf2 + base);   // residual (bf16 stream)
      float r0 = fmaf(acc[0], inv, bgA.x); r0 = r0>0.f?r0:0.f; r0 += bf_lo(ho.x);
      float r1 = fmaf(acc[1], inv, bgA.y); r1 = r1>0.f?r1:0.f; r1 += bf_hi(ho.x);
      float r2 = fmaf(acc[2], inv, bgA.z); r2 = r2>0.f?r2:0.f; r2 += bf_lo(ho.y);
      float r3 = fmaf(acc[3], inv, bgA.w); r3 = r3>0.f?r3:0.f; r3 += bf_hi(ho.y);
      float r4 = fmaf(acc[4], inv, bgB.x); r4 = r4>0.f?r4:0.f; r4 += bf_lo(ho.z);
      float r5 = fmaf(acc[5], inv, bgB.y); r5 = r5>0.f?r5:0.f; r5 += bf_hi(ho.z);
      float r6 = fmaf(acc[6], inv, bgB.z); r6 = r6>0.f?r6:0.f; r6 += bf_lo(ho.w);
      float r7 = fmaf(acc[7], inv, bgB.w); r7 = r7>0.f?r7:0.f; r7 += bf_hi(ho.w);
      uint4 pk;
      pk.x = pack2bf(r0,r1); pk.y = pack2bf(r2,r3);
      pk.z = pack2bf(r4,r5); pk.w = pack2bf(r6,r7);
      *(uint4*)(hbf2 + base) = pk;
    }
    i = inext; start = nstart; end = nend; esi = nes; edi = ned;
  }
}

// ---------------- global_add_pool (batch sorted -> run accumulate), bf16 in ------------
__global__ __launch_bounds__(256)
void k_pool(const unsigned* __restrict__ hbf2, const int* __restrict__ batch,
            float* __restrict__ pooled){
  int lane = threadIdx.x & 63, w = threadIdx.x >> 6;
  int n0 = blockIdx.x*128 + w*32;
  if (n0 >= N_NODES) return;
  int nEnd = n0 + 32; if (nEnd > N_NODES) nEnd = N_NODES;
  int cur = batch[n0];
  float a0 = 0.f, a1 = 0.f;
  for (int n = n0; n < nEnd; n++){
    int b = batch[n];
    if (b != cur){
      atomicAdd(&pooled[cur*128 + 2*lane],     a0);
      atomicAdd(&pooled[cur*128 + 2*lane + 1], a1);
      a0 = 0.f; a1 = 0.f; cur = b;
    }
    unsigned u = hbf2[((unsigned)n<<6) | lane];
    a0 += bf_lo(u); a1 += bf_hi(u);
  }
  atomicAdd(&pooled[cur*128 + 2*lane],     a0);
  atomicAdd(&pooled[cur*128 + 2*lane + 1], a1);
}

__global__ void k_final(const float* __restrict__ pooled, const float* __restrict__ W2,
                        const float* __restrict__ b2, float* __restrict__ out){
  int gid = blockIdx.x*256 + threadIdx.x;
  if (gid >= NG*DOUT) return;
  int r = gid >> 6, c = gid & 63;
  float acc = b2[c];
  #pragma unroll 4
  for (int k=0;k<DH;k++) acc = fmaf(pooled[r*DH+k], W2[k*DOUT+c], acc);
  out[(size_t)r*DOUT + c] = acc;
}

extern "C" void kernel_launch(void* const* d_in, const int* in_sizes, int n_in,
                              void* d_out, int out_size, void* d_ws, size_t ws_size,
                              hipStream_t stream){
  const float* x     = (const float*)d_in[0];
  const int*   ei    = (const int*)d_in[1];
  const int*   batch = (const int*)d_in[2];
  const float* W1    = (const float*)d_in[3];
  const float* b1    = (const float*)d_in[4];
  const float* Wg    = (const float*)d_in[5];
  const float* avs   = (const float*)d_in[6];
  const float* avd   = (const float*)d_in[7];
  const float* bgv   = (const float*)d_in[8];
  const float* W2    = (const float*)d_in[9];
  const float* b2    = (const float*)d_in[10];
  float* out = (float*)d_out;

  char* ws = (char*)d_ws;
  unsigned short* hbf = (unsigned short*)ws;       ws += (size_t)N_NODES*DH*2;   // residual stream (bf16)
  unsigned short* hp  = (unsigned short*)ws;       ws += (size_t)N_NODES*DH*2;   // GEMM out (bf16)
  float* es       = (float*)ws;                    ws += (size_t)N_NODES*4;
  float* ed       = (float*)ws;                    ws += (size_t)N_NODES*4;
  float* pooled   = (float*)ws;                    ws += NG*DH*4;
  unsigned short* Wt = (unsigned short*)ws;        ws += 4*16384*2;
  int* counts     = (int*)ws;                      ws += (size_t)N_NODES*4;      // counts+bsum: one memset
  int* bsum       = (int*)ws;                      ws += 64*4;
  int* row_ptr    = (int*)ws;                      ws += ((size_t)N_NODES+1)*4;
  int* rank       = (int*)ws;                      ws += (size_t)N_EDGES*4;
  int* col_src    = (int*)ws;                      ws += (size_t)N_EDGES*4;

  const int* esrc = ei;
  const int* edst = ei + N_EDGES;

  hipMemsetAsync(counts, 0, (N_NODES + 64)*sizeof(int), stream);   // counts + bsum flags

  // K1: edge histogram + weight transpose/cast + pooled zero
  k_hist<<<1024, 256, 0, stream>>>(edst, counts, rank, W1, Wg, Wt, pooled);
  // K2: mlp1 GEMM (391 blocks) ∥ full row_ptr scan via decoupled lookback (25 blocks)
  k_lin1_scan<<<LB + SCAN_BLOCKS, 512, 0, stream>>>(x, Wt, b1, hbf, counts, bsum, row_ptr);
  // K3: layer-0 GEMM + es/ed (391 blocks) ∥ CSR scatter (633 blocks)
  k_lin_scatter<<<1024, 512, 0, stream>>>(hbf, Wt + 16384, avs, avd,
                                          hp, es, ed, esrc, edst, rank, row_ptr, col_src);
  // K4: layer-0 aggregation
  k_gat_agg<<<AGG_BLOCKS, 256, 0, stream>>>((const unsigned*)hp, es, ed,
                                            row_ptr, col_src, bgv, (unsigned*)hbf);
  // layers 1,2
  for (int l = 1; l < 3; l++){
    k_linear_mfma<false><<<LB, 512, 0, stream>>>(hbf, Wt + (size_t)(l+1)*16384, nullptr,
                                                 avs + l*DH, avd + l*DH,
                                                 hp, es, ed, N_NODES);
    k_gat_agg<<<AGG_BLOCKS, 256, 0, stream>>>((const unsigned*)hp, es, ed,
                                              row_ptr, col_src, bgv + l*DH,
                                              (unsigned*)hbf);
  }
  // K9: pool (391 blocks, run-accumulate, ~100k atomics) + K10: final linear
  k_pool<<<(N_NODES+127)/128, 256, 0, stream>>>((const unsigned*)hbf, batch, pooled);
  k_final<<<(NG*DOUT+255)/256, 256, 0, stream>>>(pooled, W2, b2, out);
}

// Round 5
// 278.821 us; speedup vs baseline: 1.2001x; 1.0355x over previous
//
#include <hip/hip_runtime.h>
#include <hip/hip_fp8.h>

#define N_NODES 50000
#define N_EDGES 600000
#define DH 128
#define DOUT 64
#define NG 64
#define SLOPE 0.2f
#define LB 391   // GEMM blocks: (N_NODES+127)/128
#define SCAN_BLOCKS 25

using short8  = __attribute__((ext_vector_type(8))) short;
using floatx4 = __attribute__((ext_vector_type(4))) float;

__device__ __forceinline__ float leaky(float v){ return fmaxf(v, SLOPE*v); }
__device__ __forceinline__ unsigned f2bf(float x){
  unsigned u = __float_as_uint(x);
  return (u + 0x7fffu + ((u>>16)&1u)) >> 16;          // RNE bf16
}
#if __has_builtin(__builtin_amdgcn_cvt_pk_bf16_f32)
__device__ __forceinline__ unsigned pack2bf(float a, float b){
  auto t = __builtin_amdgcn_cvt_pk_bf16_f32(a, b);
  unsigned u; __builtin_memcpy(&u, &t, 4); return u;
}
#else
__device__ __forceinline__ unsigned pack2bf(float a, float b){
  return f2bf(a) | (f2bf(b) << 16);
}
#endif
__device__ __forceinline__ float bf_lo(unsigned u){ return __uint_as_float(u<<16); }
__device__ __forceinline__ float bf_hi(unsigned u){ return __uint_as_float(u & 0xffff0000u); }

// fp8 e4m3 (OCP, gfx950-native) pack/unpack: hp rows stored as fp8 -> gather bytes halve
#if __has_builtin(__builtin_amdgcn_cvt_pk_fp8_f32) && __has_builtin(__builtin_amdgcn_cvt_pk_f32_fp8)
__device__ __forceinline__ unsigned pack4fp8(float a, float b, float c, float d){
  int v = __builtin_amdgcn_cvt_pk_fp8_f32(a, b, 0, false);
  v = __builtin_amdgcn_cvt_pk_fp8_f32(c, d, v, true);
  return (unsigned)v;
}
__device__ __forceinline__ void dec4fp8(unsigned u, float* f){
  auto lo = __builtin_amdgcn_cvt_pk_f32_fp8((int)u, false);
  auto hi = __builtin_amdgcn_cvt_pk_f32_fp8((int)u, true);
  f[0]=lo[0]; f[1]=lo[1]; f[2]=hi[0]; f[3]=hi[1];
}
#else
__device__ __forceinline__ unsigned pack4fp8(float a, float b, float c, float d){
  __hip_fp8_e4m3 qa(a), qb(b), qc(c), qd(d);
  return (unsigned)qa.__x | ((unsigned)qb.__x<<8) | ((unsigned)qc.__x<<16) | ((unsigned)qd.__x<<24);
}
__device__ __forceinline__ void dec4fp8(unsigned u, float* f){
  __hip_fp8_e4m3 q;
  q.__x=(__hip_fp8_storage_t)(u&0xff);       f[0]=(float)q;
  q.__x=(__hip_fp8_storage_t)((u>>8)&0xff);  f[1]=(float)q;
  q.__x=(__hip_fp8_storage_t)((u>>16)&0xff); f[2]=(float)q;
  q.__x=(__hip_fp8_storage_t)((u>>24)&0xff); f[3]=(float)q;
}
#endif

__device__ __forceinline__ int ld_acq(int* p){
  return __hip_atomic_load(p, __ATOMIC_ACQUIRE, __HIP_MEMORY_SCOPE_AGENT);
}
__device__ __forceinline__ void st_rel(int* p, int v){
  __hip_atomic_store(p, v, __ATOMIC_RELEASE, __HIP_MEMORY_SCOPE_AGENT);
}

// ---------------- CSR build + weight prep + pooled zero --------------------------------
__global__ __launch_bounds__(256)
void k_hist(const int* __restrict__ dst, int* __restrict__ counts,
            int* __restrict__ rank,
            const float* __restrict__ W1, const float* __restrict__ Wg,
            unsigned short* __restrict__ Wt, float* __restrict__ pooled){
  int gid = blockIdx.x*256 + threadIdx.x;
  if (gid < 4*16384){                          // weight prep rides along
    int mi = gid >> 14, r = gid & 16383;
    int k = r >> 7, n = r & 127;
    const float* src = (mi==0) ? W1 : (Wg + (size_t)(mi-1)*16384);
    Wt[(size_t)mi*16384 + (size_t)n*128 + k] = (unsigned short)f2bf(src[k*128 + n]);
  }
  if (gid < NG*DH) pooled[gid] = 0.f;          // pool accumulator zero rides along
  int stride = gridDim.x*256;
  for (int e = gid; e < N_EDGES; e += stride){
    rank[e] = atomicAdd(&counts[dst[e]], 1);
  }
}

// ---------------- MFMA GEMM body (transposed D), fused es/ed ---------------------------
// 512 thr / 8 waves / 128 nodes per block. Wt: [n][k] bf16 staged in LDS (+8 pad).
// OUT8: GAT-layer output stored fp8 e4m3 (gather payload); else bf16 (residual stream).
template<bool AFP32, bool OUT8>
__device__ __forceinline__
void lin_body(const void* __restrict__ Av,
              const unsigned short* __restrict__ Wt,
              const float* __restrict__ bias,
              const float* __restrict__ avs, const float* __restrict__ avd,
              void* __restrict__ outV,
              float* __restrict__ es, float* __restrict__ ed, int nrows,
              int bid, unsigned short* wlds){
  int tid = threadIdx.x;
  #pragma unroll
  for (int i=0;i<4;i++){
    int flat = i*4096 + tid*8;
    int n = flat >> 7, kb = flat & 127;
    *(short8*)&wlds[n*136 + kb] = *(const short8*)(Wt + flat);
  }
  __syncthreads();

  int wid = tid >> 6, lane = tid & 63;
  int l15 = lane & 15, quad = lane >> 4;
  int R0 = bid*128 + wid*16;
  int node = R0 + l15;
  int arow = node < nrows ? node : nrows-1;

  floatx4 acc[8];
  #pragma unroll
  for (int nt=0;nt<8;nt++){ acc[nt][0]=0.f; acc[nt][1]=0.f; acc[nt][2]=0.f; acc[nt][3]=0.f; }

  #pragma unroll
  for (int k0=0;k0<128;k0+=32){
    short8 a;                                   // node fragment (B operand)
    if (AFP32){
      const float* Ap = (const float*)Av + (size_t)arow*128 + quad*8 + k0;
      float4 v0 = *(const float4*)Ap;
      float4 v1 = *(const float4*)(Ap+4);
      union { short8 s; unsigned u[4]; } cv;
      cv.u[0]=pack2bf(v0.x,v0.y); cv.u[1]=pack2bf(v0.z,v0.w);
      cv.u[2]=pack2bf(v1.x,v1.y); cv.u[3]=pack2bf(v1.z,v1.w);
      a = cv.s;
    } else {
      a = *(const short8*)((const unsigned short*)Av + (size_t)arow*128 + quad*8 + k0);
    }
    const unsigned short* bp = &wlds[l15*136 + quad*8 + k0];
    #pragma unroll
    for (int nt=0;nt<8;nt++){
      short8 b = *(const short8*)(bp + nt*16*136);   // Wt fragment (A operand)
      acc[nt] = __builtin_amdgcn_mfma_f32_16x16x32_bf16(b, a, acc[nt], 0,0,0);
    }
  }

  bool nv = node < nrows;
  float ps = 0.f, pd = 0.f;
  #pragma unroll
  for (int nt=0;nt<8;nt++){
    int f0 = nt*16 + quad*4;                  // 4 consecutive features for this lane
    float4 bb = make_float4(0.f,0.f,0.f,0.f);
    if (bias) bb = *(const float4*)(bias + f0);
    float v0 = acc[nt][0]+bb.x, v1 = acc[nt][1]+bb.y;
    float v2 = acc[nt][2]+bb.z, v3 = acc[nt][3]+bb.w;
    if (es){
      float4 a4 = *(const float4*)(avs + f0);
      float4 d4 = *(const float4*)(avd + f0);
      ps = fmaf(v0,a4.x, fmaf(v1,a4.y, fmaf(v2,a4.z, fmaf(v3,a4.w, ps))));
      pd = fmaf(v0,d4.x, fmaf(v1,d4.y, fmaf(v2,d4.z, fmaf(v3,d4.w, pd))));
    }
    if (nv){
      if constexpr (OUT8){
        *(unsigned*)((char*)outV + (size_t)node*128 + f0) = pack4fp8(v0,v1,v2,v3);
      } else {
        uint2 pk; pk.x = pack2bf(v0,v1); pk.y = pack2bf(v2,v3);
        *(uint2*)((unsigned short*)outV + (size_t)node*128 + f0) = pk;
      }
    }
  }
  if (es){
    ps += __shfl_xor(ps, 16, 64); ps += __shfl_xor(ps, 32, 64);
    pd += __shfl_xor(pd, 16, 64); pd += __shfl_xor(pd, 32, 64);
    if (quad==0 && nv){ es[node]=ps; ed[node]=pd; }
  }
}

template<bool AFP32, bool OUT8>
__global__ __launch_bounds__(512)
void k_linear_mfma(const void* __restrict__ Av,
                   const unsigned short* __restrict__ Wt,
                   const float* __restrict__ bias,
                   const float* __restrict__ avs, const float* __restrict__ avd,
                   void* __restrict__ outV,
                   float* __restrict__ es, float* __restrict__ ed, int nrows){
  __shared__ unsigned short wlds[128*136];
  lin_body<AFP32,OUT8>(Av, Wt, bias, avs, avd, outV, es, ed, nrows, blockIdx.x, wlds);
}

// ---------------- fat kernel: mlp1 GEMM (blocks <LB) ∥ FULL row_ptr scan (>=LB) --------
__global__ __launch_bounds__(512)
void k_lin1_scan(const float* __restrict__ x, const unsigned short* __restrict__ Wt,
                 const float* __restrict__ b1, unsigned short* __restrict__ hbf,
                 const int* __restrict__ counts, int* __restrict__ bsum,
                 int* __restrict__ row_ptr){
  __shared__ unsigned short wlds[128*136];
  if ((int)blockIdx.x >= LB){
    int* sb1 = (int*)wlds;          // reuse GEMM LDS: 512 ints scan + 33 ints lookback
    int* lk  = sb1 + 512;
    int sbid = blockIdx.x - LB;     // 0..24
    int t = threadIdx.x;
    int base = sbid*2048;
    int c[4]; int s=0;
    int idx0 = base + t*4;
    #pragma unroll
    for (int j=0;j<4;j++){ int idx = idx0+j; c[j] = (idx<N_NODES)? counts[idx]:0; s += c[j]; }
    sb1[t]=s; __syncthreads();
    for (int off=1; off<512; off<<=1){
      int v = (t>=off)? sb1[t-off] : 0;
      __syncthreads();
      sb1[t]+=v;
      __syncthreads();
    }
    int pre   = sb1[t]-s;           // exclusive prefix within this scan block
    int total = sb1[511];           // block aggregate
    if (t==0){ __threadfence(); st_rel(&bsum[sbid], total+1); }   // publish (flag: +1)
    int lv = 0;
    if (t < sbid){                  // lookback: spin on lower-indexed aggregates
      int v;
      do { v = ld_acq(&bsum[t]); } while (v == 0);
      lv = v - 1;
    }
    if (t < 32) lk[t] = lv;
    __syncthreads();
    if (t==0){ int b=0; for (int q=0;q<sbid;q++) b += lk[q]; lk[32]=b; }
    __syncthreads();
    int boff = lk[32];
    int run = pre + boff;
    #pragma unroll
    for (int j=0;j<4;j++){
      int idx = idx0+j;
      if (idx < N_NODES){ row_ptr[idx] = run; run += c[j]; }
    }
    if (sbid == SCAN_BLOCKS-1 && t == 0) row_ptr[N_NODES] = boff + total;  // == N_EDGES
    return;
  }
  lin_body<true,false>(x, Wt, b1, nullptr, nullptr, hbf, nullptr, nullptr, N_NODES,
                       blockIdx.x, wlds);
}

// ---------------- fat kernel: layer-0 GEMM (blocks <LB) ∥ CSR scatter (blocks >=LB) ----
__global__ __launch_bounds__(512)
void k_lin_scatter(const unsigned short* __restrict__ hbf,
                   const unsigned short* __restrict__ Wt,
                   const float* __restrict__ avs, const float* __restrict__ avd,
                   void* __restrict__ hp,
                   float* __restrict__ es, float* __restrict__ ed,
                   const int* __restrict__ esrc, const int* __restrict__ edst,
                   const int* __restrict__ rank, const int* __restrict__ row_ptr,
                   int* __restrict__ col_src){
  if ((int)blockIdx.x >= LB){
    int e0 = (blockIdx.x - LB)*512 + threadIdx.x;
    const int stride = (1024 - LB)*512;
    for (int e = e0; e < N_EDGES; e += stride){
      col_src[row_ptr[edst[e]] + rank[e]] = esrc[e];
    }
    return;
  }
  __shared__ unsigned short wlds[128*136];
  lin_body<false,true>(hbf, Wt, nullptr, avs, avd, hp, es, ed, N_NODES, blockIdx.x, wlds);
}

// ---------------- GAT aggregation: fp8 rows, 4-edges-per-VMEM gather -------------------
// quad q (lane>>4) owns edge t+q; each lane loads uint2 (8B = 8 fp8 features) -> one VMEM
// instruction fetches 4 edge-rows (512B). Rows are 128B fp8: 2x less traffic, hp 6.4MB
// (~62% per-XCD-L2-resident vs 31% at bf16). Decode via v_cvt_pk_f32_fp8 (cheaper than
// bf16 shift/and). s/w broadcast via __shfl; acc[8] fp32; cross-quad shfl_xor reduce.
#define AGG_BLOCKS 3126
__global__ __launch_bounds__(256)
void k_gat_agg(const uint2* __restrict__ hp8, const float* __restrict__ es,
               const float* __restrict__ ed, const int* __restrict__ row_ptr,
               const int* __restrict__ col_src, const float* __restrict__ bg,
               unsigned* __restrict__ hbf2){
  int lane = threadIdx.x & 63;
  int sub = lane & 15, quad = lane >> 4;
  int subw = sub << 2;                          // bf16 word offset (residual stream)
  int wav0 = blockIdx.x*4 + (threadIdx.x >> 6);
  const int NW = AGG_BLOCKS*4;

  int i = wav0;
  int start=0, end=0; float esi=0.f, edi=0.f;
  if (i < N_NODES){
    start = row_ptr[i]; end = row_ptr[i+1];
    esi = es[i]; edi = ed[i];
  }
  while (i < N_NODES){
    int inext = i + NW;
    int nstart=0, nend=0; float nes=0.f, ned=0.f;
    if (inext < N_NODES){                       // prefetch next node's scalars
      nstart = row_ptr[inext]; nend = row_ptr[inext+1];
      nes = es[inext]; ned = ed[inext];
    }
    float m0 = leaky(esi + edi);                // self score: softmax recentering
    float acc[8];
    if (quad == 0){                             // self weight exp(0)=1, quad0 only
      uint2 u = hp8[(unsigned)i*16u + sub];
      dec4fp8(u.x, acc); dec4fp8(u.y, acc+4);
    } else {
      #pragma unroll
      for (int r=0;r<8;r++) acc[r]=0.f;
    }
    float zl = (lane==0) ? 1.f : 0.f;

    for (int c0 = start; c0 < end; c0 += 64){
      int j = c0 + lane;
      bool valid = j < end;
      int sreg = valid ? col_src[j] : 0;
      float e = leaky(es[sreg] + edi);
      float w = valid ? __expf(e - m0) : 0.f;   // invalid lanes: w=0 (safe in groups)
      zl += w;
      int len = end - c0; if (len > 64) len = 64;
      int lenp = (len + 3) & ~3;                // round up to whole groups of 4
      int t = 0;
      for (; t + 8 <= lenp; t += 8){            // 2 groups in flight
        int iA = t + quad,          iB = t + 4 + quad;
        int   sA = __shfl(sreg, iA, 64),  sB = __shfl(sreg, iB, 64);
        float wA = __shfl(w,    iA, 64),  wB = __shfl(w,    iB, 64);
        uint2 uA = hp8[(unsigned)sA*16u + sub];
        uint2 uB = hp8[(unsigned)sB*16u + sub];
        float fA[8]; dec4fp8(uA.x, fA); dec4fp8(uA.y, fA+4);
        float fB[8]; dec4fp8(uB.x, fB); dec4fp8(uB.y, fB+4);
        #pragma unroll
        for (int r=0;r<8;r++) acc[r]=fmaf(wA, fA[r], acc[r]);
        #pragma unroll
        for (int r=0;r<8;r++) acc[r]=fmaf(wB, fB[r], acc[r]);
      }
      if (t < lenp){
        int iA = t + quad;
        int   sA = __shfl(sreg, iA, 64);
        float wA = __shfl(w,    iA, 64);
        uint2 uA = hp8[(unsigned)sA*16u + sub];
        float fA[8]; dec4fp8(uA.x, fA); dec4fp8(uA.y, fA+4);
        #pragma unroll
        for (int r=0;r<8;r++) acc[r]=fmaf(wA, fA[r], acc[r]);
      }
    }

    // cross-quad reduce: 4 edge-slots accumulated the same feature set
    #pragma unroll
    for (int r=0;r<8;r++){
      acc[r] += __shfl_xor(acc[r], 16, 64);
      acc[r] += __shfl_xor(acc[r], 32, 64);
    }
    float z = zl;
    #pragma unroll
    for (int off=32; off>0; off>>=1) z += __shfl_xor(z, off, 64);
    float inv = 1.f / z;

    if (quad == 0){
      float4 bgA = *(const float4*)(bg + sub*8);
      float4 bgB = *(const float4*)(bg + sub*8 + 4);
      unsigned base = ((unsigned)i<<6) | subw;
      uint4 ho = *(const uint4*)(hbf2 + base);   // residual (bf16 stream)
      float r0 = fmaf(acc[0], inv, bgA.x); r0 = r0>0.f?r0:0.f; r0 += bf_lo(ho.x);
      float r1 = fmaf(acc[1], inv, bgA.y); r1 = r1>0.f?r1:0.f; r1 += bf_hi(ho.x);
      float r2 = fmaf(acc[2], inv, bgA.z); r2 = r2>0.f?r2:0.f; r2 += bf_lo(ho.y);
      float r3 = fmaf(acc[3], inv, bgA.w); r3 = r3>0.f?r3:0.f; r3 += bf_hi(ho.y);
      float r4 = fmaf(acc[4], inv, bgB.x); r4 = r4>0.f?r4:0.f; r4 += bf_lo(ho.z);
      float r5 = fmaf(acc[5], inv, bgB.y); r5 = r5>0.f?r5:0.f; r5 += bf_hi(ho.z);
      float r6 = fmaf(acc[6], inv, bgB.z); r6 = r6>0.f?r6:0.f; r6 += bf_lo(ho.w);
      float r7 = fmaf(acc[7], inv, bgB.w); r7 = r7>0.f?r7:0.f; r7 += bf_hi(ho.w);
      uint4 pk;
      pk.x = pack2bf(r0,r1); pk.y = pack2bf(r2,r3);
      pk.z = pack2bf(r4,r5); pk.w = pack2bf(r6,r7);
      *(uint4*)(hbf2 + base) = pk;
    }
    i = inext; start = nstart; end = nend; esi = nes; edi = ned;
  }
}

// ---------------- global_add_pool (batch sorted -> run accumulate), bf16 in ------------
__global__ __launch_bounds__(256)
void k_pool(const unsigned* __restrict__ hbf2, const int* __restrict__ batch,
            float* __restrict__ pooled){
  int lane = threadIdx.x & 63, w = threadIdx.x >> 6;
  int n0 = blockIdx.x*128 + w*32;
  if (n0 >= N_NODES) return;
  int nEnd = n0 + 32; if (nEnd > N_NODES) nEnd = N_NODES;
  int cur = batch[n0];
  float a0 = 0.f, a1 = 0.f;
  for (int n = n0; n < nEnd; n++){
    int b = batch[n];
    if (b != cur){
      atomicAdd(&pooled[cur*128 + 2*lane],     a0);
      atomicAdd(&pooled[cur*128 + 2*lane + 1], a1);
      a0 = 0.f; a1 = 0.f; cur = b;
    }
    unsigned u = hbf2[((unsigned)n<<6) | lane];
    a0 += bf_lo(u); a1 += bf_hi(u);
  }
  atomicAdd(&pooled[cur*128 + 2*lane],     a0);
  atomicAdd(&pooled[cur*128 + 2*lane + 1], a1);
}

__global__ void k_final(const float* __restrict__ pooled, const float* __restrict__ W2,
                        const float* __restrict__ b2, float* __restrict__ out){
  int gid = blockIdx.x*256 + threadIdx.x;
  if (gid >= NG*DOUT) return;
  int r = gid >> 6, c = gid & 63;
  float acc = b2[c];
  #pragma unroll 4
  for (int k=0;k<DH;k++) acc = fmaf(pooled[r*DH+k], W2[k*DOUT+c], acc);
  out[(size_t)r*DOUT + c] = acc;
}

extern "C" void kernel_launch(void* const* d_in, const int* in_sizes, int n_in,
                              void* d_out, int out_size, void* d_ws, size_t ws_size,
                              hipStream_t stream){
  const float* x     = (const float*)d_in[0];
  const int*   ei    = (const int*)d_in[1];
  const int*   batch = (const int*)d_in[2];
  const float* W1    = (const float*)d_in[3];
  const float* b1    = (const float*)d_in[4];
  const float* Wg    = (const float*)d_in[5];
  const float* avs   = (const float*)d_in[6];
  const float* avd   = (const float*)d_in[7];
  const float* bgv   = (const float*)d_in[8];
  const float* W2    = (const float*)d_in[9];
  const float* b2    = (const float*)d_in[10];
  float* out = (float*)d_out;

  char* ws = (char*)d_ws;
  unsigned short* hbf = (unsigned short*)ws;       ws += (size_t)N_NODES*DH*2;   // residual stream (bf16)
  void* hp        = (void*)ws;                     ws += (size_t)N_NODES*DH;     // GEMM out (fp8 e4m3)
  float* es       = (float*)ws;                    ws += (size_t)N_NODES*4;
  float* ed       = (float*)ws;                    ws += (size_t)N_NODES*4;
  float* pooled   = (float*)ws;                    ws += NG*DH*4;
  unsigned short* Wt = (unsigned short*)ws;        ws += 4*16384*2;
  int* counts     = (int*)ws;                      ws += (size_t)N_NODES*4;      // counts+bsum: one memset
  int* bsum       = (int*)ws;                      ws += 64*4;
  int* row_ptr    = (int*)ws;                      ws += ((size_t)N_NODES+1)*4;
  int* rank       = (int*)ws;                      ws += (size_t)N_EDGES*4;
  int* col_src    = (int*)ws;                      ws += (size_t)N_EDGES*4;

  const int* esrc = ei;
  const int* edst = ei + N_EDGES;

  hipMemsetAsync(counts, 0, (N_NODES + 64)*sizeof(int), stream);   // counts + bsum flags

  // K1: edge histogram + weight transpose/cast + pooled zero
  k_hist<<<1024, 256, 0, stream>>>(edst, counts, rank, W1, Wg, Wt, pooled);
  // K2: mlp1 GEMM (391 blocks) ∥ full row_ptr scan via decoupled lookback (25 blocks)
  k_lin1_scan<<<LB + SCAN_BLOCKS, 512, 0, stream>>>(x, Wt, b1, hbf, counts, bsum, row_ptr);
  // K3: layer-0 GEMM + es/ed (391 blocks) ∥ CSR scatter (633 blocks)
  k_lin_scatter<<<1024, 512, 0, stream>>>(hbf, Wt + 16384, avs, avd,
                                          hp, es, ed, esrc, edst, rank, row_ptr, col_src);
  // K4: layer-0 aggregation (fp8 gather)
  k_gat_agg<<<AGG_BLOCKS, 256, 0, stream>>>((const uint2*)hp, es, ed,
                                            row_ptr, col_src, bgv, (unsigned*)hbf);
  // layers 1,2
  for (int l = 1; l < 3; l++){
    k_linear_mfma<false,true><<<LB, 512, 0, stream>>>(hbf, Wt + (size_t)(l+1)*16384, nullptr,
                                                      avs + l*DH, avd + l*DH,
                                                      hp, es, ed, N_NODES);
    k_gat_agg<<<AGG_BLOCKS, 256, 0, stream>>>((const uint2*)hp, es, ed,
                                              row_ptr, col_src, bgv + l*DH,
                                              (unsigned*)hbf);
  }
  // K9: pool (391 blocks, run-accumulate, ~100k atomics) + K10: final linear
  k_pool<<<(N_NODES+127)/128, 256, 0, stream>>>((const unsigned*)hbf, batch, pooled);
  k_final<<<(NG*DOUT+255)/256, 256, 0, stream>>>(pooled, W2, b2, out);
}